// Round 1
// baseline (8831.754 us; speedup 1.0000x reference)
//
#include <hip/hip_runtime.h>

// MoEUT time-series decoder, fp32 correctness-first baseline.
// L=3 layers: LN -> QKV -> RoPE -> full softmax attention -> Oproj(+res)
//             -> LN -> sigmoid-gate top2/8 MoE (dense compute, masked) (+res)
// Final: LN(lnf_t) + LN(lnf_d) on last token only -> [B, NOUT] head.

#define LNUM 3
#define D 1024
#define H 16
#define HD 64
#define E 8
#define EH 256
#define B 2
#define S 1024
#define DIN 32
#define NOUT 8
#define EPS 1e-5f
#define TOK (B * S)
#define TQ 8

// ---------------- reductions ----------------
__device__ inline float block_reduce_sum256(float v, float* scratch) {
  int lane = threadIdx.x & 63, wv = threadIdx.x >> 6;
#pragma unroll
  for (int off = 32; off; off >>= 1) v += __shfl_down(v, off);
  __syncthreads();
  if (lane == 0) scratch[wv] = v;
  __syncthreads();
  return scratch[0] + scratch[1] + scratch[2] + scratch[3];
}

// ---------------- LayerNorm (one block per token, 256 thr) ----------------
__global__ __launch_bounds__(256) void ln_kernel(const float* __restrict__ in,
                                                 const float* __restrict__ g,
                                                 const float* __restrict__ bta,
                                                 float* __restrict__ out) {
  int token = blockIdx.x;
  int tid = threadIdx.x;
  const float* p = in + (size_t)token * D;
  __shared__ float scratch[4];
  float x[4];
  float s = 0.f, sq = 0.f;
#pragma unroll
  for (int i = 0; i < 4; i++) {
    x[i] = p[tid + i * 256];
    s += x[i];
    sq += x[i] * x[i];
  }
  s = block_reduce_sum256(s, scratch);
  sq = block_reduce_sum256(sq, scratch);
  float mean = s * (1.f / D);
  float var = sq * (1.f / D) - mean * mean;
  float inv = rsqrtf(var + EPS);
  float* op = out + (size_t)token * D;
#pragma unroll
  for (int i = 0; i < 4; i++) {
    int d = tid + i * 256;
    op[d] = (x[i] - mean) * inv * g[d] + bta[d];
  }
}

// ---------------- generic tiled GEMM ----------------
// C[M,N] (+)= epi(A[M,Kd] @ B + bias), B row-major [Kd,N] or transB [N,Kd].
// epi: (+bias) -> relu? -> *rowScale[row*rsStride]?
#define BM 64
#define BN 64
#define BKT 16
__global__ __launch_bounds__(256) void gemm_kernel(
    const float* __restrict__ A, const float* __restrict__ Bw,
    const float* __restrict__ bias, const float* __restrict__ rowScale,
    int rsStride, float* __restrict__ C, int M, int N, int Kd, int transB,
    int accum, int relu) {
  __shared__ float As[BKT][BM + 1];
  __shared__ float Bs[BKT][BN + 1];
  int bm = blockIdx.y * BM, bn = blockIdx.x * BN;
  int tid = threadIdx.x;
  int tx = tid & 15, ty = tid >> 4;
  float acc[4][4] = {};
  for (int k0 = 0; k0 < Kd; k0 += BKT) {
#pragma unroll
    for (int j = 0; j < 4; j++) {
      int i = tid + j * 256;
      int r = i >> 4, c = i & 15;
      As[c][r] = A[(size_t)(bm + r) * Kd + k0 + c];
    }
    if (!transB) {
#pragma unroll
      for (int j = 0; j < 4; j++) {
        int i = tid + j * 256;
        int c = i >> 6, n = i & 63;
        Bs[c][n] = Bw[(size_t)(k0 + c) * N + bn + n];
      }
    } else {
#pragma unroll
      for (int j = 0; j < 4; j++) {
        int i = tid + j * 256;
        int n = i >> 4, c = i & 15;
        Bs[c][n] = Bw[(size_t)(bn + n) * Kd + k0 + c];
      }
    }
    __syncthreads();
#pragma unroll
    for (int kk = 0; kk < BKT; kk++) {
      float a[4], bb[4];
#pragma unroll
      for (int i2 = 0; i2 < 4; i2++) a[i2] = As[kk][ty * 4 + i2];
#pragma unroll
      for (int i2 = 0; i2 < 4; i2++) bb[i2] = Bs[kk][tx * 4 + i2];
#pragma unroll
      for (int i2 = 0; i2 < 4; i2++)
#pragma unroll
        for (int j2 = 0; j2 < 4; j2++) acc[i2][j2] += a[i2] * bb[j2];
    }
    __syncthreads();
  }
#pragma unroll
  for (int i2 = 0; i2 < 4; i2++) {
    int row = bm + ty * 4 + i2;
    float rs = rowScale ? rowScale[(size_t)row * rsStride] : 1.f;
#pragma unroll
    for (int j2 = 0; j2 < 4; j2++) {
      int col = bn + tx * 4 + j2;
      float vv = acc[i2][j2];
      if (bias) vv += bias[col];
      if (relu) vv = fmaxf(vv, 0.f);
      vv *= rs;
      if (accum)
        C[(size_t)row * N + col] += vv;
      else
        C[(size_t)row * N + col] = vv;
    }
  }
}

// ---------------- RoPE in-place on q,k ----------------
__global__ __launch_bounds__(256) void rope_kernel(float* __restrict__ q,
                                                   float* __restrict__ k) {
  int s = blockIdx.x, b = blockIdx.y;
  int tid = threadIdx.x;
  for (int i = tid; i < H * (HD / 2); i += 256) {  // 512 (head, pair) items
    int hh = i >> 5, j = i & 31;
    // inv_freq = 10000^(-2j/HD); log2(10000)=13.287712379549449
    float inv = exp2f(-(2.f * j / HD) * 13.2877123795494f);
    float ang = (float)s * inv;
    float c = cosf(ang), sn = sinf(ang);
    size_t base = ((size_t)(b * S + s)) * D + hh * HD;
    float a0 = q[base + j], a1 = q[base + j + 32];
    q[base + j] = a0 * c - a1 * sn;
    q[base + j + 32] = a1 * c + a0 * sn;
    float b0 = k[base + j], b1 = k[base + j + 32];
    k[base + j] = b0 * c - b1 * sn;
    k[base + j + 32] = b1 * c + b0 * sn;
  }
}

// ---------------- attention: block = (8 queries, head, batch) ----------------
__global__ __launch_bounds__(256) void attn_kernel(const float* __restrict__ q,
                                                   const float* __restrict__ k,
                                                   const float* __restrict__ v,
                                                   float* __restrict__ o) {
  int qt = blockIdx.x, hh = blockIdx.y, b = blockIdx.z;
  int tid = threadIdx.x;
  __shared__ float sc[TQ][S];   // 32 KB scores
  __shared__ float qs[TQ][HD];  // 2 KB q tile
  for (int i = tid; i < TQ * HD; i += 256) {
    int qi = i >> 6, j = i & 63;
    qs[qi][j] = q[((size_t)(b * S + qt * TQ + qi)) * D + hh * HD + j];
  }
  __syncthreads();
  const float scale = 0.125f;  // HD^-0.5
  for (int t = tid; t < S; t += 256) {
    const float* kp = k + ((size_t)(b * S + t)) * D + hh * HD;
    float acc[TQ];
#pragma unroll
    for (int qi = 0; qi < TQ; qi++) acc[qi] = 0.f;
    for (int j = 0; j < HD; j++) {
      float kv = kp[j];
#pragma unroll
      for (int qi = 0; qi < TQ; qi++) acc[qi] += qs[qi][j] * kv;
    }
#pragma unroll
    for (int qi = 0; qi < TQ; qi++) sc[qi][t] = acc[qi] * scale;
  }
  __syncthreads();
  int lane = tid & 63, wv = tid >> 6;
  // each wave owns 2 score rows: softmax with wave-only reductions
  for (int r = 0; r < 2; r++) {
    int qi = wv * 2 + r;
    float mx = -1e30f;
    for (int t = lane; t < S; t += 64) mx = fmaxf(mx, sc[qi][t]);
#pragma unroll
    for (int off = 32; off; off >>= 1) mx = fmaxf(mx, __shfl_down(mx, off));
    mx = __shfl(mx, 0);
    float sum = 0.f;
    for (int t = lane; t < S; t += 64) {
      float e = __expf(sc[qi][t] - mx);
      sc[qi][t] = e;
      sum += e;
    }
#pragma unroll
    for (int off = 32; off; off >>= 1) sum += __shfl_down(sum, off);
    sum = __shfl(sum, 0);
    float is = 1.f / sum;
    for (int t = lane; t < S; t += 64) sc[qi][t] *= is;
  }
  __syncthreads();
  // o[qi][lane] = sum_t p[qi][t] * v[t][lane]; wave wv does rows 2wv,2wv+1
  for (int r = 0; r < 2; r++) {
    int qi = wv * 2 + r;
    const float* vp = v + ((size_t)(b * S)) * D + hh * HD + lane;
    float a0 = 0.f, a1 = 0.f;
    for (int t = 0; t < S; t += 2) {
      a0 += sc[qi][t] * vp[(size_t)t * D];
      a1 += sc[qi][t + 1] * vp[(size_t)(t + 1) * D];
    }
    o[((size_t)(b * S + qt * TQ + qi)) * D + hh * HD + lane] = a0 + a1;
  }
}

// ---------------- gate: sigmoid(xn @ selw), top-2 mask ----------------
__global__ __launch_bounds__(256) void gate_kernel(const float* __restrict__ xn,
                                                   const float* __restrict__ selw,
                                                   float* __restrict__ m) {
  int token = blockIdx.x;
  int tid = threadIdx.x;
  const float* p = xn + (size_t)token * D;
  float acc[E];
#pragma unroll
  for (int e = 0; e < E; e++) acc[e] = 0.f;
  for (int d = tid; d < D; d += 256) {
    float xv = p[d];
#pragma unroll
    for (int e = 0; e < E; e++) acc[e] += xv * selw[d * E + e];
  }
  __shared__ float red[4 * E];
  int lane = tid & 63, wv = tid >> 6;
#pragma unroll
  for (int e = 0; e < E; e++) {
    float vv = acc[e];
#pragma unroll
    for (int off = 32; off; off >>= 1) vv += __shfl_down(vv, off);
    if (lane == 0) red[wv * E + e] = vv;
  }
  __syncthreads();
  if (tid == 0) {
    float g[E];
    for (int e = 0; e < E; e++) {
      float sv = red[e] + red[E + e] + red[2 * E + e] + red[3 * E + e];
      g[e] = 1.f / (1.f + __expf(-sv));
    }
    // top-2, first-occurrence ties (matches lax.top_k)
    int i0 = 0;
    for (int e = 1; e < E; e++)
      if (g[e] > g[i0]) i0 = e;
    int i1 = -1;
    for (int e = 0; e < E; e++) {
      if (e == i0) continue;
      if (i1 < 0 || g[e] > g[i1]) i1 = e;
    }
    float mm[E];
    for (int e = 0; e < E; e++) mm[e] = 0.f;
    mm[i0] = g[i0];
    mm[i1] = g[i1];
    for (int e = 0; e < E; e++) m[(size_t)token * E + e] = mm[e];
  }
}

// ---------------- final head: last token only ----------------
__global__ __launch_bounds__(256) void final_kernel(
    const float* __restrict__ h, const float* __restrict__ tg,
    const float* __restrict__ tb, const float* __restrict__ dg,
    const float* __restrict__ db, const float* __restrict__ ow,
    const float* __restrict__ ob, float* __restrict__ out) {
  int b = blockIdx.x;
  int tid = threadIdx.x;
  __shared__ float scratch[4];
  __shared__ float yf[D];
  const float* p = h + ((size_t)(b * S + (S - 1))) * D;
  float x[4];
  float s = 0.f, sq = 0.f;
#pragma unroll
  for (int i = 0; i < 4; i++) {
    x[i] = p[tid + i * 256];
    s += x[i];
    sq += x[i] * x[i];
  }
  s = block_reduce_sum256(s, scratch);
  sq = block_reduce_sum256(sq, scratch);
  float mean = s * (1.f / D);
  float inv = rsqrtf(sq * (1.f / D) - mean * mean + EPS);
  float y[4];
  s = 0.f;
  sq = 0.f;
#pragma unroll
  for (int i = 0; i < 4; i++) {
    int d = tid + i * 256;
    y[i] = (x[i] - mean) * inv * tg[d] + tb[d];
    s += y[i];
    sq += y[i] * y[i];
  }
  s = block_reduce_sum256(s, scratch);
  sq = block_reduce_sum256(sq, scratch);
  float mean2 = s * (1.f / D);
  float inv2 = rsqrtf(sq * (1.f / D) - mean2 * mean2 + EPS);
#pragma unroll
  for (int i = 0; i < 4; i++) {
    int d = tid + i * 256;
    yf[d] = (y[i] - mean2) * inv2 * dg[d] + db[d];
  }
  __syncthreads();
  for (int oo = 0; oo < NOUT; oo++) {
    float part = 0.f;
    for (int d = tid; d < D; d += 256) part += yf[d] * ow[(size_t)oo * D + d];
    part = block_reduce_sum256(part, scratch);
    if (tid == 0) out[b * NOUT + oo] = part + ob[oo];
  }
}

extern "C" void kernel_launch(void* const* d_in, const int* in_sizes, int n_in,
                              void* d_out, int out_size, void* d_ws,
                              size_t ws_size, hipStream_t stream) {
  const float* x = (const float*)d_in[0];
  const float* ln1_g = (const float*)d_in[1];
  const float* ln1_b = (const float*)d_in[2];
  const float* qw = (const float*)d_in[3];
  const float* qb = (const float*)d_in[4];
  const float* kw = (const float*)d_in[5];
  const float* kb = (const float*)d_in[6];
  const float* vw = (const float*)d_in[7];
  const float* vb = (const float*)d_in[8];
  const float* ow = (const float*)d_in[9];
  const float* ob = (const float*)d_in[10];
  const float* ln2_g = (const float*)d_in[11];
  const float* ln2_b = (const float*)d_in[12];
  const float* selw = (const float*)d_in[13];
  const float* w1 = (const float*)d_in[14];
  const float* w2 = (const float*)d_in[15];
  const float* lntg = (const float*)d_in[16];
  const float* lntb = (const float*)d_in[17];
  const float* lndg = (const float*)d_in[18];
  const float* lndb = (const float*)d_in[19];
  const float* inw = (const float*)d_in[20];
  const float* inb = (const float*)d_in[21];
  const float* outw = (const float*)d_in[22];
  const float* outb = (const float*)d_in[23];
  float* out = (float*)d_out;

  // workspace layout (fp32): 6x [TOK,D] + gates [TOK,E] + mid [TOK,EH] ~ 50 MB
  float* h = (float*)d_ws;
  float* xn = h + (size_t)TOK * D;
  float* q = xn + (size_t)TOK * D;
  float* k = q + (size_t)TOK * D;
  float* v = k + (size_t)TOK * D;
  float* o = v + (size_t)TOK * D;
  float* gm = o + (size_t)TOK * D;
  float* mid = gm + (size_t)TOK * E;

  dim3 gD(D / BN, TOK / BM);    // N=1024 grids
  dim3 gEH(EH / BN, TOK / BM);  // N=256 grids

  // input proj: h = x @ in_w^T + in_b
  gemm_kernel<<<gD, 256, 0, stream>>>(x, inw, inb, nullptr, 0, h, TOK, D, DIN,
                                      1, 0, 0);
  for (int l = 0; l < LNUM; l++) {
    ln_kernel<<<TOK, 256, 0, stream>>>(h, ln1_g + l * D, ln1_b + l * D, xn);
    gemm_kernel<<<gD, 256, 0, stream>>>(xn, qw + (size_t)l * D * D, qb + l * D,
                                        nullptr, 0, q, TOK, D, D, 0, 0, 0);
    gemm_kernel<<<gD, 256, 0, stream>>>(xn, kw + (size_t)l * D * D, kb + l * D,
                                        nullptr, 0, k, TOK, D, D, 0, 0, 0);
    gemm_kernel<<<gD, 256, 0, stream>>>(xn, vw + (size_t)l * D * D, vb + l * D,
                                        nullptr, 0, v, TOK, D, D, 0, 0, 0);
    rope_kernel<<<dim3(S, B), 256, 0, stream>>>(q, k);
    attn_kernel<<<dim3(S / TQ, H, B), 256, 0, stream>>>(q, k, v, o);
    // h += o @ ow^T + ob
    gemm_kernel<<<gD, 256, 0, stream>>>(o, ow + (size_t)l * D * D, ob + l * D,
                                        nullptr, 0, h, TOK, D, D, 1, 1, 0);
    ln_kernel<<<TOK, 256, 0, stream>>>(h, ln2_g + l * D, ln2_b + l * D, xn);
    gate_kernel<<<TOK, 256, 0, stream>>>(xn, selw + (size_t)l * D * E, gm);
    for (int e = 0; e < E; e++) {
      // mid = relu(xn @ w1[e]) * gate[token,e]   (dense, gate zeroes non-top2)
      gemm_kernel<<<gEH, 256, 0, stream>>>(
          xn, w1 + ((size_t)(l * E + e)) * D * EH, nullptr, gm + e, E, mid, TOK,
          EH, D, 0, 0, 1);
      // h += mid @ w2[e]
      gemm_kernel<<<gD, 256, 0, stream>>>(mid,
                                          w2 + ((size_t)(l * E + e)) * EH * D,
                                          nullptr, nullptr, 0, h, TOK, D, EH, 0,
                                          1, 0);
    }
  }
  final_kernel<<<B, 256, 0, stream>>>(h, lntg, lntb, lndg, lndb, outw, outb,
                                      out);
}

// Round 2
// 4212.991 us; speedup vs baseline: 2.0963x; 2.0963x over previous
//
#include <hip/hip_runtime.h>

// MoEUT time-series decoder, round 2: bf16 MFMA GEMMs (m97-style structure),
// batched QKV (z=3), dense MoE with experts batched in z (w1) and folded into
// the K dimension (w2, K=2048, no atomics). Attention still fp32 (next round).

#define LNUM 3
#define D 1024
#define H 16
#define HD 64
#define E 8
#define EH 256
#define B 2
#define S 1024
#define DIN 32
#define NOUT 8
#define EPS 1e-5f
#define TOK (B * S)
#define TQ 8

typedef __bf16 bf16x8 __attribute__((ext_vector_type(8)));
typedef float fx4 __attribute__((ext_vector_type(4)));

// ---------------- reductions ----------------
__device__ inline float block_reduce_sum256(float v, float* scratch) {
  int lane = threadIdx.x & 63, wv = threadIdx.x >> 6;
#pragma unroll
  for (int off = 32; off; off >>= 1) v += __shfl_down(v, off);
  __syncthreads();
  if (lane == 0) scratch[wv] = v;
  __syncthreads();
  return scratch[0] + scratch[1] + scratch[2] + scratch[3];
}

// ---------------- LayerNorm (one block per token, 256 thr) ----------------
// Writes fp32 out and bf16 shadow.
__global__ __launch_bounds__(256) void ln_kernel(const float* __restrict__ in,
                                                 const float* __restrict__ g,
                                                 const float* __restrict__ bta,
                                                 float* __restrict__ out,
                                                 __bf16* __restrict__ outb) {
  int token = blockIdx.x;
  int tid = threadIdx.x;
  const float* p = in + (size_t)token * D;
  __shared__ float scratch[4];
  float x[4];
  float s = 0.f, sq = 0.f;
#pragma unroll
  for (int i = 0; i < 4; i++) {
    x[i] = p[tid + i * 256];
    s += x[i];
    sq += x[i] * x[i];
  }
  s = block_reduce_sum256(s, scratch);
  sq = block_reduce_sum256(sq, scratch);
  float mean = s * (1.f / D);
  float var = sq * (1.f / D) - mean * mean;
  float inv = rsqrtf(var + EPS);
  float* op = out + (size_t)token * D;
  __bf16* obp = outb + (size_t)token * D;
#pragma unroll
  for (int i = 0; i < 4; i++) {
    int d = tid + i * 256;
    float y = (x[i] - mean) * inv * g[d] + bta[d];
    op[d] = y;
    obp[d] = (__bf16)y;
  }
}

// ---------------- fp32 tiled GEMM (input projection only, K=32) ----------
#define BM 64
#define BN 64
#define BKT 16
__global__ __launch_bounds__(256) void gemm_kernel(
    const float* __restrict__ A, const float* __restrict__ Bw,
    const float* __restrict__ bias, float* __restrict__ C, int M, int N,
    int Kd) {
  // transB fixed: B[n,k] = Bw[n*Kd+k]
  __shared__ float As[BKT][BM + 1];
  __shared__ float Bs[BKT][BN + 1];
  int bm = blockIdx.y * BM, bn = blockIdx.x * BN;
  int tid = threadIdx.x;
  int tx = tid & 15, ty = tid >> 4;
  float acc[4][4] = {};
  for (int k0 = 0; k0 < Kd; k0 += BKT) {
#pragma unroll
    for (int j = 0; j < 4; j++) {
      int i = tid + j * 256;
      int r = i >> 4, c = i & 15;
      As[c][r] = A[(size_t)(bm + r) * Kd + k0 + c];
    }
#pragma unroll
    for (int j = 0; j < 4; j++) {
      int i = tid + j * 256;
      int n = i >> 4, c = i & 15;
      Bs[c][n] = Bw[(size_t)(bn + n) * Kd + k0 + c];
    }
    __syncthreads();
#pragma unroll
    for (int kk = 0; kk < BKT; kk++) {
      float a[4], bb[4];
#pragma unroll
      for (int i2 = 0; i2 < 4; i2++) a[i2] = As[kk][ty * 4 + i2];
#pragma unroll
      for (int i2 = 0; i2 < 4; i2++) bb[i2] = Bs[kk][tx * 4 + i2];
#pragma unroll
      for (int i2 = 0; i2 < 4; i2++)
#pragma unroll
        for (int j2 = 0; j2 < 4; j2++) acc[i2][j2] += a[i2] * bb[j2];
    }
    __syncthreads();
  }
#pragma unroll
  for (int i2 = 0; i2 < 4; i2++) {
    int row = bm + ty * 4 + i2;
#pragma unroll
    for (int j2 = 0; j2 < 4; j2++) {
      int col = bn + tx * 4 + j2;
      C[(size_t)row * N + col] = acc[i2][j2] + bias[col];
    }
  }
}

// ---------------- bf16 MFMA GEMM, 128x128 tile, BK=32 -------------------
// C[M,N] = epi(A[M,K] @ Bt[N,K]^T). A row-major lda, Bt row-major (ld = K).
// z batching: A += z*aZ, Bt += z*bZ, bias += z*biasZ, out addr += z*cZ.
// epi: (+bias) -> relu? -> *rowScale[row*rsLd+z]? -> {bf16 out | fp32 (+=)}.
__global__ __launch_bounds__(256) void mfma_gemm(
    const __bf16* __restrict__ A, int lda, long long aZ,
    const __bf16* __restrict__ Bt, long long bZ, const float* __restrict__ bias,
    long long biasZ, float* __restrict__ C, __bf16* __restrict__ Cbf, int ldc,
    long long cZ, const float* __restrict__ rowScale, int rsLd, int K,
    int accum, int relu) {
  __shared__ __bf16 As[128 * 32];
  __shared__ __bf16 Bs[128 * 32];
  int z = blockIdx.z;
  int bm = blockIdx.y * 128, bn = blockIdx.x * 128;
  int tid = threadIdx.x, lane = tid & 63, wv = tid >> 6;
  int wr = wv >> 1, wc = wv & 1;
  int half = lane >> 4, mrow = lane & 15;
  const __bf16* Ab = A + (size_t)z * aZ + (size_t)bm * lda;
  const __bf16* Bb = Bt + (size_t)z * bZ + (size_t)bn * K;
  fx4 acc[4][4] = {};
  for (int k0 = 0; k0 < K; k0 += 32) {
#pragma unroll
    for (int it = 0; it < 2; it++) {
      int c = tid + it * 256;
      int row = c >> 2, kc = (c & 3) << 3;
      __builtin_amdgcn_global_load_lds(
          (const __attribute__((address_space(1))) void*)(Ab +
                                                          (size_t)row * lda +
                                                          k0 + kc),
          (__attribute__((address_space(3))) void*)(As + c * 8), 16, 0, 0);
      __builtin_amdgcn_global_load_lds(
          (const __attribute__((address_space(1))) void*)(Bb + (size_t)row * K +
                                                          k0 + kc),
          (__attribute__((address_space(3))) void*)(Bs + c * 8), 16, 0, 0);
    }
    __syncthreads();
    bf16x8 af[4], bfr[4];
#pragma unroll
    for (int i = 0; i < 4; i++)
      af[i] = *(const bf16x8*)(As + (wr * 64 + i * 16 + mrow) * 32 + half * 8);
#pragma unroll
    for (int j = 0; j < 4; j++)
      bfr[j] = *(const bf16x8*)(Bs + (wc * 64 + j * 16 + mrow) * 32 + half * 8);
#pragma unroll
    for (int i = 0; i < 4; i++)
#pragma unroll
      for (int j = 0; j < 4; j++)
        acc[i][j] = __builtin_amdgcn_mfma_f32_16x16x32_bf16(af[i], bfr[j],
                                                            acc[i][j], 0, 0, 0);
    __syncthreads();
  }
#pragma unroll
  for (int i = 0; i < 4; i++) {
#pragma unroll
    for (int r = 0; r < 4; r++) {
      int row = bm + wr * 64 + i * 16 + half * 4 + r;
      float rs = rowScale ? rowScale[(size_t)row * rsLd + z] : 1.f;
#pragma unroll
      for (int j = 0; j < 4; j++) {
        int col = bn + wc * 64 + j * 16 + mrow;
        float val = acc[i][j][r];
        if (bias) val += bias[(size_t)z * biasZ + col];
        if (relu) val = fmaxf(val, 0.f);
        val *= rs;
        size_t addr = (size_t)z * cZ + (size_t)row * ldc + col;
        if (Cbf)
          Cbf[addr] = (__bf16)val;
        else if (accum)
          C[addr] += val;
        else
          C[addr] = val;
      }
    }
  }
}

// ---------------- fp32 -> bf16 transpose+convert -------------------------
// src fp32 [R][C] (+ z*srcZ). dst bf16: dst[c*dstLd + z*dstZ + r].
__global__ void transpose_cvt(const float* __restrict__ src, long long srcZ,
                              __bf16* __restrict__ dst, long long dstZ, int R,
                              int C, int dstLd) {
  __shared__ float t[32][33];
  int r0 = blockIdx.y * 32, c0 = blockIdx.x * 32;
  int z = blockIdx.z;
  src += (size_t)z * srcZ;
  int tx = threadIdx.x, ty = threadIdx.y;
#pragma unroll
  for (int i = 0; i < 4; i++) {
    int r = r0 + ty + i * 8;
    t[ty + i * 8][tx] = src[(size_t)r * C + c0 + tx];
  }
  __syncthreads();
#pragma unroll
  for (int i = 0; i < 4; i++) {
    int c = c0 + ty + i * 8;
    dst[(size_t)c * dstLd + (size_t)z * dstZ + r0 + tx] =
        (__bf16)t[tx][ty + i * 8];
  }
}

// ---------------- fp32 -> bf16 elementwise convert ------------------------
__global__ void cvt_kernel(const float* __restrict__ s, __bf16* __restrict__ d,
                           int n) {
  for (int i = blockIdx.x * 256 + threadIdx.x; i < n; i += gridDim.x * 256)
    d[i] = (__bf16)s[i];
}

// ---------------- concat 3 biases ----------------------------------------
__global__ void copy3(const float* __restrict__ a, const float* __restrict__ b,
                      const float* __restrict__ c, float* __restrict__ dst) {
  int i = blockIdx.x * 256 + threadIdx.x;
  if (i < D)
    dst[i] = a[i];
  else if (i < 2 * D)
    dst[i] = b[i - D];
  else if (i < 3 * D)
    dst[i] = c[i - 2 * D];
}

// ---------------- RoPE in-place on q,k ----------------
__global__ __launch_bounds__(256) void rope_kernel(float* __restrict__ q,
                                                   float* __restrict__ k) {
  int s = blockIdx.x, b = blockIdx.y;
  int tid = threadIdx.x;
  for (int i = tid; i < H * (HD / 2); i += 256) {
    int hh = i >> 5, j = i & 31;
    float inv = exp2f(-(2.f * j / HD) * 13.2877123795494f);
    float ang = (float)s * inv;
    float c = cosf(ang), sn = sinf(ang);
    size_t base = ((size_t)(b * S + s)) * D + hh * HD;
    float a0 = q[base + j], a1 = q[base + j + 32];
    q[base + j] = a0 * c - a1 * sn;
    q[base + j + 32] = a1 * c + a0 * sn;
    float b0 = k[base + j], b1 = k[base + j + 32];
    k[base + j] = b0 * c - b1 * sn;
    k[base + j + 32] = b1 * c + b0 * sn;
  }
}

// ---------------- attention (fp32), bf16 output ----------------
__global__ __launch_bounds__(256) void attn_kernel(const float* __restrict__ q,
                                                   const float* __restrict__ k,
                                                   const float* __restrict__ v,
                                                   __bf16* __restrict__ obf) {
  int qt = blockIdx.x, hh = blockIdx.y, b = blockIdx.z;
  int tid = threadIdx.x;
  __shared__ float sc[TQ][S];   // 32 KB scores
  __shared__ float qs[TQ][HD];  // 2 KB q tile
  for (int i = tid; i < TQ * HD; i += 256) {
    int qi = i >> 6, j = i & 63;
    qs[qi][j] = q[((size_t)(b * S + qt * TQ + qi)) * D + hh * HD + j];
  }
  __syncthreads();
  const float scale = 0.125f;  // HD^-0.5
  for (int t = tid; t < S; t += 256) {
    const float4* kp = (const float4*)(k + ((size_t)(b * S + t)) * D + hh * HD);
    float accq[TQ];
#pragma unroll
    for (int qi = 0; qi < TQ; qi++) accq[qi] = 0.f;
    for (int j = 0; j < HD / 4; j++) {
      float4 kv = kp[j];
#pragma unroll
      for (int qi = 0; qi < TQ; qi++)
        accq[qi] += qs[qi][j * 4] * kv.x + qs[qi][j * 4 + 1] * kv.y +
                    qs[qi][j * 4 + 2] * kv.z + qs[qi][j * 4 + 3] * kv.w;
    }
#pragma unroll
    for (int qi = 0; qi < TQ; qi++) sc[qi][t] = accq[qi] * scale;
  }
  __syncthreads();
  int lane = tid & 63, wv = tid >> 6;
  for (int r = 0; r < 2; r++) {
    int qi = wv * 2 + r;
    float mx = -1e30f;
    for (int t = lane; t < S; t += 64) mx = fmaxf(mx, sc[qi][t]);
#pragma unroll
    for (int off = 32; off; off >>= 1) mx = fmaxf(mx, __shfl_down(mx, off));
    mx = __shfl(mx, 0);
    float sum = 0.f;
    for (int t = lane; t < S; t += 64) {
      float e = __expf(sc[qi][t] - mx);
      sc[qi][t] = e;
      sum += e;
    }
#pragma unroll
    for (int off = 32; off; off >>= 1) sum += __shfl_down(sum, off);
    sum = __shfl(sum, 0);
    float is = 1.f / sum;
    for (int t = lane; t < S; t += 64) sc[qi][t] *= is;
  }
  __syncthreads();
  // PV: wave wv owns rows 2wv, 2wv+1; shared v load, lane = head dim
  int qi0 = wv * 2, qi1 = qi0 + 1;
  const float* vp = v + ((size_t)(b * S)) * D + hh * HD + lane;
  float a0 = 0.f, a1 = 0.f;
  for (int t = 0; t < S; t++) {
    float vv = vp[(size_t)t * D];
    a0 += sc[qi0][t] * vv;
    a1 += sc[qi1][t] * vv;
  }
  obf[((size_t)(b * S + qt * TQ + qi0)) * D + hh * HD + lane] = (__bf16)a0;
  obf[((size_t)(b * S + qt * TQ + qi1)) * D + hh * HD + lane] = (__bf16)a1;
}

// ---------------- gate: sigmoid(xn @ selw), top-2 mask ----------------
__global__ __launch_bounds__(256) void gate_kernel(
    const float* __restrict__ xn, const float* __restrict__ selw,
    float* __restrict__ m) {
  int token = blockIdx.x;
  int tid = threadIdx.x;
  const float* p = xn + (size_t)token * D;
  float acc[E];
#pragma unroll
  for (int e = 0; e < E; e++) acc[e] = 0.f;
  for (int d = tid; d < D; d += 256) {
    float xv = p[d];
#pragma unroll
    for (int e = 0; e < E; e++) acc[e] += xv * selw[d * E + e];
  }
  __shared__ float red[4 * E];
  int lane = tid & 63, wv = tid >> 6;
#pragma unroll
  for (int e = 0; e < E; e++) {
    float vv = acc[e];
#pragma unroll
    for (int off = 32; off; off >>= 1) vv += __shfl_down(vv, off);
    if (lane == 0) red[wv * E + e] = vv;
  }
  __syncthreads();
  if (tid == 0) {
    float g[E];
    for (int e = 0; e < E; e++) {
      float sv = red[e] + red[E + e] + red[2 * E + e] + red[3 * E + e];
      g[e] = 1.f / (1.f + __expf(-sv));
    }
    int i0 = 0;
    for (int e = 1; e < E; e++)
      if (g[e] > g[i0]) i0 = e;
    int i1 = -1;
    for (int e = 0; e < E; e++) {
      if (e == i0) continue;
      if (i1 < 0 || g[e] > g[i1]) i1 = e;
    }
    float mm[E];
    for (int e = 0; e < E; e++) mm[e] = 0.f;
    mm[i0] = g[i0];
    mm[i1] = g[i1];
    for (int e = 0; e < E; e++) m[(size_t)token * E + e] = mm[e];
  }
}

// ---------------- final head: last token only ----------------
__global__ __launch_bounds__(256) void final_kernel(
    const float* __restrict__ h, const float* __restrict__ tg,
    const float* __restrict__ tb, const float* __restrict__ dg,
    const float* __restrict__ db, const float* __restrict__ ow,
    const float* __restrict__ ob, float* __restrict__ out) {
  int b = blockIdx.x;
  int tid = threadIdx.x;
  __shared__ float scratch[4];
  __shared__ float yf[D];
  const float* p = h + ((size_t)(b * S + (S - 1))) * D;
  float x[4];
  float s = 0.f, sq = 0.f;
#pragma unroll
  for (int i = 0; i < 4; i++) {
    x[i] = p[tid + i * 256];
    s += x[i];
    sq += x[i] * x[i];
  }
  s = block_reduce_sum256(s, scratch);
  sq = block_reduce_sum256(sq, scratch);
  float mean = s * (1.f / D);
  float inv = rsqrtf(sq * (1.f / D) - mean * mean + EPS);
  float y[4];
  s = 0.f;
  sq = 0.f;
#pragma unroll
  for (int i = 0; i < 4; i++) {
    int d = tid + i * 256;
    y[i] = (x[i] - mean) * inv * tg[d] + tb[d];
    s += y[i];
    sq += y[i] * y[i];
  }
  s = block_reduce_sum256(s, scratch);
  sq = block_reduce_sum256(sq, scratch);
  float mean2 = s * (1.f / D);
  float inv2 = rsqrtf(sq * (1.f / D) - mean2 * mean2 + EPS);
#pragma unroll
  for (int i = 0; i < 4; i++) {
    int d = tid + i * 256;
    yf[d] = (y[i] - mean2) * inv2 * dg[d] + db[d];
  }
  __syncthreads();
  for (int oo = 0; oo < NOUT; oo++) {
    float part = 0.f;
    for (int d = tid; d < D; d += 256) part += yf[d] * ow[(size_t)oo * D + d];
    part = block_reduce_sum256(part, scratch);
    if (tid == 0) out[b * NOUT + oo] = part + ob[oo];
  }
}

extern "C" void kernel_launch(void* const* d_in, const int* in_sizes, int n_in,
                              void* d_out, int out_size, void* d_ws,
                              size_t ws_size, hipStream_t stream) {
  const float* x = (const float*)d_in[0];
  const float* ln1_g = (const float*)d_in[1];
  const float* ln1_b = (const float*)d_in[2];
  const float* qw = (const float*)d_in[3];
  const float* qb = (const float*)d_in[4];
  const float* kw = (const float*)d_in[5];
  const float* kb = (const float*)d_in[6];
  const float* vw = (const float*)d_in[7];
  const float* vb = (const float*)d_in[8];
  const float* ow = (const float*)d_in[9];
  const float* ob = (const float*)d_in[10];
  const float* ln2_g = (const float*)d_in[11];
  const float* ln2_b = (const float*)d_in[12];
  const float* selw = (const float*)d_in[13];
  const float* w1 = (const float*)d_in[14];
  const float* w2 = (const float*)d_in[15];
  const float* lntg = (const float*)d_in[16];
  const float* lntb = (const float*)d_in[17];
  const float* lndg = (const float*)d_in[18];
  const float* lndb = (const float*)d_in[19];
  const float* inw = (const float*)d_in[20];
  const float* inb = (const float*)d_in[21];
  const float* outw = (const float*)d_in[22];
  const float* outb = (const float*)d_in[23];
  float* out = (float*)d_out;

  // ---- workspace layout (~72 MB) ----
  float* h = (float*)d_ws;                    // TOK*D
  float* xn = h + (size_t)TOK * D;            // TOK*D
  float* qkv = xn + (size_t)TOK * D;          // 3*TOK*D
  float* gm = qkv + (size_t)3 * TOK * D;      // TOK*E
  float* qkvb = gm + (size_t)TOK * E;         // 3*D
  __bf16* xnb = (__bf16*)(qkvb + 3 * D);      // TOK*D
  __bf16* obf = xnb + (size_t)TOK * D;        // TOK*D
  __bf16* midb = obf + (size_t)TOK * D;       // TOK*E*EH
  __bf16* qkvt = midb + (size_t)TOK * E * EH; // 3*D*D
  __bf16* owt = qkvt + (size_t)3 * D * D;     // D*D
  __bf16* w1t = owt + (size_t)D * D;          // E*EH*D  ([e][eh][d])
  __bf16* w2t = w1t + (size_t)E * EH * D;     // D*E*EH  ([d][e*EH+eh])

  float* q = qkv;
  float* k = qkv + (size_t)TOK * D;
  float* v = qkv + (size_t)2 * TOK * D;

  // input proj: h = x @ in_w^T + in_b  (fp32, K=32)
  gemm_kernel<<<dim3(D / BN, TOK / BM), 256, 0, stream>>>(x, inw, inb, h, TOK,
                                                          D, DIN);
  for (int l = 0; l < LNUM; l++) {
    ln_kernel<<<TOK, 256, 0, stream>>>(h, ln1_g + l * D, ln1_b + l * D, xn,
                                       xnb);
    // weight prep: qkvt[w][n][k] = {q,k,v}w[l][k][n]
    transpose_cvt<<<dim3(D / 32, D / 32, 1), dim3(32, 8), 0, stream>>>(
        qw + (size_t)l * D * D, 0, qkvt, 0, D, D, D);
    transpose_cvt<<<dim3(D / 32, D / 32, 1), dim3(32, 8), 0, stream>>>(
        kw + (size_t)l * D * D, 0, qkvt + (size_t)D * D, 0, D, D, D);
    transpose_cvt<<<dim3(D / 32, D / 32, 1), dim3(32, 8), 0, stream>>>(
        vw + (size_t)l * D * D, 0, qkvt + (size_t)2 * D * D, 0, D, D, D);
    copy3<<<12, 256, 0, stream>>>(qb + l * D, kb + l * D, vb + l * D, qkvb);
    // q,k,v = xn @ {q,k,v}w + bias   (z = 0..2)
    mfma_gemm<<<dim3(D / 128, TOK / 128, 3), 256, 0, stream>>>(
        xnb, D, 0, qkvt, (long long)D * D, qkvb, D, qkv, nullptr, D,
        (long long)TOK * D, nullptr, 0, D, 0, 0);
    rope_kernel<<<dim3(S, B), 256, 0, stream>>>(q, k);
    attn_kernel<<<dim3(S / TQ, H, B), 256, 0, stream>>>(q, k, v, obf);
    // h += o @ ow^T + ob  (ow already [N][K] for the transposed product)
    cvt_kernel<<<512, 256, 0, stream>>>(ow + (size_t)l * D * D, owt, D * D);
    mfma_gemm<<<dim3(D / 128, TOK / 128, 1), 256, 0, stream>>>(
        obf, D, 0, owt, 0, ob + l * D, 0, h, nullptr, D, 0, nullptr, 0, D, 1,
        0);
    ln_kernel<<<TOK, 256, 0, stream>>>(h, ln2_g + l * D, ln2_b + l * D, xn,
                                       xnb);
    gate_kernel<<<TOK, 256, 0, stream>>>(xn, selw + (size_t)l * D * E, gm);
    // w1t[e][eh][d] = w1[l][e][d][eh]
    transpose_cvt<<<dim3(EH / 32, D / 32, E), dim3(32, 8), 0, stream>>>(
        w1 + (size_t)l * E * D * EH, (long long)D * EH, w1t, (long long)EH * D,
        D, EH, D);
    // mid[token][e*EH+eh] = relu(xn @ w1[e] ) * gate[token][e]  (bf16 out)
    mfma_gemm<<<dim3(EH / 128, TOK / 128, E), 256, 0, stream>>>(
        xnb, D, 0, w1t, (long long)EH * D, nullptr, 0, nullptr, midb, E * EH,
        EH, gm, E, D, 0, 1);
    // w2t[d][e*EH+eh] = w2[l][e][eh][d]  (experts folded into K)
    transpose_cvt<<<dim3(D / 32, EH / 32, E), dim3(32, 8), 0, stream>>>(
        w2 + (size_t)l * E * EH * D, (long long)EH * D, w2t, EH, EH, D, E * EH);
    // h += mid @ w2stacked   (M=2048, N=1024, K=2048)
    mfma_gemm<<<dim3(D / 128, TOK / 128, 1), 256, 0, stream>>>(
        midb, E * EH, 0, w2t, 0, nullptr, 0, h, nullptr, D, 0, nullptr, 0,
        E * EH, 1, 0);
  }
  final_kernel<<<B, 256, 0, stream>>>(h, lntg, lntb, lndg, lndb, outw, outb,
                                      out);
}

// Round 3
// 994.304 us; speedup vs baseline: 8.8823x; 4.2371x over previous
//
#include <hip/hip_runtime.h>

// MoEUT time-series decoder, round 3: bf16 MFMA flash attention.
// GEMMs: m97-style 128x128 bf16 MFMA (QKV batched z=3, MoE w1 z=8,
// w2 experts folded into K=2048). QKV written bf16 directly; RoPE on bf16.

#define LNUM 3
#define D 1024
#define H 16
#define HD 64
#define E 8
#define EH 256
#define B 2
#define S 1024
#define DIN 32
#define NOUT 8
#define EPS 1e-5f
#define TOK (B * S)

typedef __bf16 bf16x8 __attribute__((ext_vector_type(8)));
typedef __bf16 bf16x4 __attribute__((ext_vector_type(4)));
typedef float fx4 __attribute__((ext_vector_type(4)));

// ---------------- reductions ----------------
__device__ inline float block_reduce_sum256(float v, float* scratch) {
  int lane = threadIdx.x & 63, wv = threadIdx.x >> 6;
#pragma unroll
  for (int off = 32; off; off >>= 1) v += __shfl_down(v, off);
  __syncthreads();
  if (lane == 0) scratch[wv] = v;
  __syncthreads();
  return scratch[0] + scratch[1] + scratch[2] + scratch[3];
}

// ---------------- LayerNorm: fp32 out + bf16 shadow ----------------
__global__ __launch_bounds__(256) void ln_kernel(const float* __restrict__ in,
                                                 const float* __restrict__ g,
                                                 const float* __restrict__ bta,
                                                 float* __restrict__ out,
                                                 __bf16* __restrict__ outb) {
  int token = blockIdx.x;
  int tid = threadIdx.x;
  const float* p = in + (size_t)token * D;
  __shared__ float scratch[4];
  float x[4];
  float s = 0.f, sq = 0.f;
#pragma unroll
  for (int i = 0; i < 4; i++) {
    x[i] = p[tid + i * 256];
    s += x[i];
    sq += x[i] * x[i];
  }
  s = block_reduce_sum256(s, scratch);
  sq = block_reduce_sum256(sq, scratch);
  float mean = s * (1.f / D);
  float var = sq * (1.f / D) - mean * mean;
  float inv = rsqrtf(var + EPS);
  float* op = out + (size_t)token * D;
  __bf16* obp = outb + (size_t)token * D;
#pragma unroll
  for (int i = 0; i < 4; i++) {
    int d = tid + i * 256;
    float y = (x[i] - mean) * inv * g[d] + bta[d];
    op[d] = y;
    obp[d] = (__bf16)y;
  }
}

// ---------------- fp32 tiled GEMM (input projection, K=32) ----------
#define BM 64
#define BN 64
#define BKT 16
__global__ __launch_bounds__(256) void gemm_kernel(
    const float* __restrict__ A, const float* __restrict__ Bw,
    const float* __restrict__ bias, float* __restrict__ C, int M, int N,
    int Kd) {
  __shared__ float As[BKT][BM + 1];
  __shared__ float Bs[BKT][BN + 1];
  int bm = blockIdx.y * BM, bn = blockIdx.x * BN;
  int tid = threadIdx.x;
  int tx = tid & 15, ty = tid >> 4;
  float acc[4][4] = {};
  for (int k0 = 0; k0 < Kd; k0 += BKT) {
#pragma unroll
    for (int j = 0; j < 4; j++) {
      int i = tid + j * 256;
      int r = i >> 4, c = i & 15;
      As[c][r] = A[(size_t)(bm + r) * Kd + k0 + c];
    }
#pragma unroll
    for (int j = 0; j < 4; j++) {
      int i = tid + j * 256;
      int n = i >> 4, c = i & 15;
      Bs[c][n] = Bw[(size_t)(bn + n) * Kd + k0 + c];
    }
    __syncthreads();
#pragma unroll
    for (int kk = 0; kk < BKT; kk++) {
      float a[4], bb[4];
#pragma unroll
      for (int i2 = 0; i2 < 4; i2++) a[i2] = As[kk][ty * 4 + i2];
#pragma unroll
      for (int i2 = 0; i2 < 4; i2++) bb[i2] = Bs[kk][tx * 4 + i2];
#pragma unroll
      for (int i2 = 0; i2 < 4; i2++)
#pragma unroll
        for (int j2 = 0; j2 < 4; j2++) acc[i2][j2] += a[i2] * bb[j2];
    }
    __syncthreads();
  }
#pragma unroll
  for (int i2 = 0; i2 < 4; i2++) {
    int row = bm + ty * 4 + i2;
#pragma unroll
    for (int j2 = 0; j2 < 4; j2++) {
      int col = bn + tx * 4 + j2;
      C[(size_t)row * N + col] = acc[i2][j2] + bias[col];
    }
  }
}

// ---------------- bf16 MFMA GEMM, 128x128 tile, BK=32 -------------------
__global__ __launch_bounds__(256) void mfma_gemm(
    const __bf16* __restrict__ A, int lda, long long aZ,
    const __bf16* __restrict__ Bt, long long bZ, const float* __restrict__ bias,
    long long biasZ, float* __restrict__ C, __bf16* __restrict__ Cbf, int ldc,
    long long cZ, const float* __restrict__ rowScale, int rsLd, int K,
    int accum, int relu) {
  __shared__ __bf16 As[128 * 32];
  __shared__ __bf16 Bs[128 * 32];
  int z = blockIdx.z;
  int bm = blockIdx.y * 128, bn = blockIdx.x * 128;
  int tid = threadIdx.x, lane = tid & 63, wv = tid >> 6;
  int wr = wv >> 1, wc = wv & 1;
  int half = lane >> 4, mrow = lane & 15;
  const __bf16* Ab = A + (size_t)z * aZ + (size_t)bm * lda;
  const __bf16* Bb = Bt + (size_t)z * bZ + (size_t)bn * K;
  fx4 acc[4][4] = {};
  for (int k0 = 0; k0 < K; k0 += 32) {
#pragma unroll
    for (int it = 0; it < 2; it++) {
      int c = tid + it * 256;
      int row = c >> 2, kc = (c & 3) << 3;
      __builtin_amdgcn_global_load_lds(
          (const __attribute__((address_space(1))) void*)(Ab +
                                                          (size_t)row * lda +
                                                          k0 + kc),
          (__attribute__((address_space(3))) void*)(As + c * 8), 16, 0, 0);
      __builtin_amdgcn_global_load_lds(
          (const __attribute__((address_space(1))) void*)(Bb + (size_t)row * K +
                                                          k0 + kc),
          (__attribute__((address_space(3))) void*)(Bs + c * 8), 16, 0, 0);
    }
    __syncthreads();
    bf16x8 af[4], bfr[4];
#pragma unroll
    for (int i = 0; i < 4; i++)
      af[i] = *(const bf16x8*)(As + (wr * 64 + i * 16 + mrow) * 32 + half * 8);
#pragma unroll
    for (int j = 0; j < 4; j++)
      bfr[j] = *(const bf16x8*)(Bs + (wc * 64 + j * 16 + mrow) * 32 + half * 8);
#pragma unroll
    for (int i = 0; i < 4; i++)
#pragma unroll
      for (int j = 0; j < 4; j++)
        acc[i][j] = __builtin_amdgcn_mfma_f32_16x16x32_bf16(af[i], bfr[j],
                                                            acc[i][j], 0, 0, 0);
    __syncthreads();
  }
#pragma unroll
  for (int i = 0; i < 4; i++) {
#pragma unroll
    for (int r = 0; r < 4; r++) {
      int row = bm + wr * 64 + i * 16 + half * 4 + r;
      float rs = rowScale ? rowScale[(size_t)row * rsLd + z] : 1.f;
#pragma unroll
      for (int j = 0; j < 4; j++) {
        int col = bn + wc * 64 + j * 16 + mrow;
        float val = acc[i][j][r];
        if (bias) val += bias[(size_t)z * biasZ + col];
        if (relu) val = fmaxf(val, 0.f);
        val *= rs;
        size_t addr = (size_t)z * cZ + (size_t)row * ldc + col;
        if (Cbf)
          Cbf[addr] = (__bf16)val;
        else if (accum)
          C[addr] += val;
        else
          C[addr] = val;
      }
    }
  }
}

// ---------------- fp32 -> bf16 transpose+convert -------------------------
__global__ void transpose_cvt(const float* __restrict__ src, long long srcZ,
                              __bf16* __restrict__ dst, long long dstZ, int R,
                              int C, int dstLd) {
  __shared__ float t[32][33];
  int r0 = blockIdx.y * 32, c0 = blockIdx.x * 32;
  int z = blockIdx.z;
  src += (size_t)z * srcZ;
  int tx = threadIdx.x, ty = threadIdx.y;
#pragma unroll
  for (int i = 0; i < 4; i++) {
    int r = r0 + ty + i * 8;
    t[ty + i * 8][tx] = src[(size_t)r * C + c0 + tx];
  }
  __syncthreads();
#pragma unroll
  for (int i = 0; i < 4; i++) {
    int c = c0 + ty + i * 8;
    dst[(size_t)c * dstLd + (size_t)z * dstZ + r0 + tx] =
        (__bf16)t[tx][ty + i * 8];
  }
}

__global__ void cvt_kernel(const float* __restrict__ s, __bf16* __restrict__ d,
                           int n) {
  for (int i = blockIdx.x * 256 + threadIdx.x; i < n; i += gridDim.x * 256)
    d[i] = (__bf16)s[i];
}

__global__ void copy3(const float* __restrict__ a, const float* __restrict__ b,
                      const float* __restrict__ c, float* __restrict__ dst) {
  int i = blockIdx.x * 256 + threadIdx.x;
  if (i < D)
    dst[i] = a[i];
  else if (i < 2 * D)
    dst[i] = b[i - D];
  else if (i < 3 * D)
    dst[i] = c[i - 2 * D];
}

// ---------------- RoPE in-place on bf16 q,k ----------------
__global__ __launch_bounds__(256) void rope_kernel_bf(__bf16* __restrict__ q,
                                                      __bf16* __restrict__ k) {
  int s = blockIdx.x, b = blockIdx.y;
  int tid = threadIdx.x;
  for (int i = tid; i < H * (HD / 2); i += 256) {
    int hh = i >> 5, j = i & 31;
    float inv = exp2f(-(2.f * j / HD) * 13.2877123795494f);
    float ang = (float)s * inv;
    float c = cosf(ang), sn = sinf(ang);
    size_t base = ((size_t)(b * S + s)) * D + hh * HD;
    float a0 = (float)q[base + j], a1 = (float)q[base + j + 32];
    q[base + j] = (__bf16)(a0 * c - a1 * sn);
    q[base + j + 32] = (__bf16)(a1 * c + a0 * sn);
    float b0 = (float)k[base + j], b1 = (float)k[base + j + 32];
    k[base + j] = (__bf16)(b0 * c - b1 * sn);
    k[base + j + 32] = (__bf16)(b1 * c + b0 * sn);
  }
}

// ---------------- bf16 MFMA flash attention ----------------
// Block: 4 waves, 64 query rows (wave w owns rows w*16..w*16+16).
// Loop over 16 K/V tiles of 64. Online softmax in C-layout registers.
#define KT_LD 72
#define VT_LD 68
#define P_LD 72
__global__ __launch_bounds__(256) void attn_mfma(const __bf16* __restrict__ qb,
                                                 const __bf16* __restrict__ kb,
                                                 const __bf16* __restrict__ vb,
                                                 __bf16* __restrict__ obf) {
  __shared__ __bf16 Kt[64 * KT_LD];  // [t][d], padded
  __shared__ __bf16 Vt[HD * VT_LD];  // [d][t], padded (transposed V)
  __shared__ __bf16 Pb[64 * P_LD];   // [qrow][t], per-wave-private slices
  int q0 = blockIdx.x * 64, hh = blockIdx.y, b = blockIdx.z;
  int tid = threadIdx.x, lane = tid & 63, wv = tid >> 6;
  int col = lane & 15, half = lane >> 4;
  const size_t headoff = (size_t)hh * HD;
  const float scale = 0.125f;  // HD^-0.5

  // Q fragments: A[m=col][k=half*8+j (+32)]
  const __bf16* qbase =
      qb + ((size_t)(b * S + q0 + wv * 16 + col)) * D + headoff;
  bf16x8 qf0 = *(const bf16x8*)(qbase + half * 8);
  bf16x8 qf1 = *(const bf16x8*)(qbase + 32 + half * 8);

  fx4 Oacc[4] = {};  // 4 n-tiles over HD=64; C-layout rows half*4+r
  float m_i[4] = {-1e30f, -1e30f, -1e30f, -1e30f};
  float l_i[4] = {0.f, 0.f, 0.f, 0.f};

  for (int t0 = 0; t0 < S; t0 += 64) {
    __syncthreads();
    // stage K tile [64][64] -> Kt[t][d]
#pragma unroll
    for (int it = 0; it < 2; it++) {
      int c = tid + it * 256;
      int row = c >> 3, off = (c & 7) * 8;
      *(bf16x8*)(Kt + row * KT_LD + off) =
          *(const bf16x8*)(kb + ((size_t)(b * S + t0 + row)) * D + headoff +
                           off);
    }
    // stage V tile transposed -> Vt[d][t]; 2x8 micro-tile per thread
    {
      int dgroup = tid & 7, tpair = tid >> 3;
      int t = tpair * 2;
      bf16x8 v0 = *(const bf16x8*)(vb + ((size_t)(b * S + t0 + t)) * D +
                                   headoff + dgroup * 8);
      bf16x8 v1 = *(const bf16x8*)(vb + ((size_t)(b * S + t0 + t + 1)) * D +
                                   headoff + dgroup * 8);
#pragma unroll
      for (int j = 0; j < 8; j++) {
        __bf16* p = Vt + (dgroup * 8 + j) * VT_LD + t;
        p[0] = v0[j];
        p[1] = v1[j];
      }
    }
    __syncthreads();

    // S = Q @ K^T
    fx4 sacc[4] = {};
#pragma unroll
    for (int n = 0; n < 4; n++) {
      bf16x8 b0 = *(const bf16x8*)(Kt + (n * 16 + col) * KT_LD + half * 8);
      bf16x8 b1 = *(const bf16x8*)(Kt + (n * 16 + col) * KT_LD + 32 + half * 8);
      sacc[n] =
          __builtin_amdgcn_mfma_f32_16x16x32_bf16(qf0, b0, sacc[n], 0, 0, 0);
      sacc[n] =
          __builtin_amdgcn_mfma_f32_16x16x32_bf16(qf1, b1, sacc[n], 0, 0, 0);
    }
    // online softmax (rows half*4+r; 16 cols of a row live in the 16-lane group)
#pragma unroll
    for (int r = 0; r < 4; r++) {
      float mx =
          fmaxf(fmaxf(sacc[0][r], sacc[1][r]), fmaxf(sacc[2][r], sacc[3][r]));
#pragma unroll
      for (int msk = 1; msk < 16; msk <<= 1)
        mx = fmaxf(mx, __shfl_xor(mx, msk));
      float nm = fmaxf(m_i[r], mx * scale);
      float alpha = __expf(m_i[r] - nm);
      m_i[r] = nm;
      l_i[r] *= alpha;
#pragma unroll
      for (int n = 0; n < 4; n++) Oacc[n][r] *= alpha;
      float part = 0.f;
      int prow = (wv * 16 + half * 4 + r) * P_LD;
#pragma unroll
      for (int n = 0; n < 4; n++) {
        float p = __expf(sacc[n][r] * scale - nm);
        part += p;
        Pb[prow + n * 16 + col] = (__bf16)p;
      }
#pragma unroll
      for (int msk = 1; msk < 16; msk <<= 1) part += __shfl_xor(part, msk);
      l_i[r] += part;
    }
    // O += P @ V  (A = P from per-wave LDS slice, B from Vt)
#pragma unroll
    for (int k0 = 0; k0 < 2; k0++) {
      bf16x8 af =
          *(const bf16x8*)(Pb + (wv * 16 + col) * P_LD + k0 * 32 + half * 8);
#pragma unroll
      for (int n = 0; n < 4; n++) {
        const __bf16* vp = Vt + (n * 16 + col) * VT_LD + k0 * 32 + half * 8;
        bf16x4 lo = *(const bf16x4*)vp;
        bf16x4 hi = *(const bf16x4*)(vp + 4);
        bf16x8 bfv;
#pragma unroll
        for (int j = 0; j < 4; j++) {
          bfv[j] = lo[j];
          bfv[4 + j] = hi[j];
        }
        Oacc[n] =
            __builtin_amdgcn_mfma_f32_16x16x32_bf16(af, bfv, Oacc[n], 0, 0, 0);
      }
    }
  }
  // epilogue: O /= l, bf16 store
#pragma unroll
  for (int r = 0; r < 4; r++) {
    float inv = 1.f / l_i[r];
    int row = q0 + wv * 16 + half * 4 + r;
    __bf16* op = obf + ((size_t)(b * S + row)) * D + headoff;
#pragma unroll
    for (int n = 0; n < 4; n++) op[n * 16 + col] = (__bf16)(Oacc[n][r] * inv);
  }
}

// ---------------- gate: sigmoid(xn @ selw), top-2 mask ----------------
__global__ __launch_bounds__(256) void gate_kernel(
    const float* __restrict__ xn, const float* __restrict__ selw,
    float* __restrict__ m) {
  int token = blockIdx.x;
  int tid = threadIdx.x;
  const float* p = xn + (size_t)token * D;
  float acc[E];
#pragma unroll
  for (int e = 0; e < E; e++) acc[e] = 0.f;
  for (int d = tid; d < D; d += 256) {
    float xv = p[d];
#pragma unroll
    for (int e = 0; e < E; e++) acc[e] += xv * selw[d * E + e];
  }
  __shared__ float red[4 * E];
  int lane = tid & 63, wv = tid >> 6;
#pragma unroll
  for (int e = 0; e < E; e++) {
    float vv = acc[e];
#pragma unroll
    for (int off = 32; off; off >>= 1) vv += __shfl_down(vv, off);
    if (lane == 0) red[wv * E + e] = vv;
  }
  __syncthreads();
  if (tid == 0) {
    float g[E];
    for (int e = 0; e < E; e++) {
      float sv = red[e] + red[E + e] + red[2 * E + e] + red[3 * E + e];
      g[e] = 1.f / (1.f + __expf(-sv));
    }
    int i0 = 0;
    for (int e = 1; e < E; e++)
      if (g[e] > g[i0]) i0 = e;
    int i1 = -1;
    for (int e = 0; e < E; e++) {
      if (e == i0) continue;
      if (i1 < 0 || g[e] > g[i1]) i1 = e;
    }
    float mm[E];
    for (int e = 0; e < E; e++) mm[e] = 0.f;
    mm[i0] = g[i0];
    mm[i1] = g[i1];
    for (int e = 0; e < E; e++) m[(size_t)token * E + e] = mm[e];
  }
}

// ---------------- final head: last token only ----------------
__global__ __launch_bounds__(256) void final_kernel(
    const float* __restrict__ h, const float* __restrict__ tg,
    const float* __restrict__ tb, const float* __restrict__ dg,
    const float* __restrict__ db, const float* __restrict__ ow,
    const float* __restrict__ ob, float* __restrict__ out) {
  int b = blockIdx.x;
  int tid = threadIdx.x;
  __shared__ float scratch[4];
  __shared__ float yf[D];
  const float* p = h + ((size_t)(b * S + (S - 1))) * D;
  float x[4];
  float s = 0.f, sq = 0.f;
#pragma unroll
  for (int i = 0; i < 4; i++) {
    x[i] = p[tid + i * 256];
    s += x[i];
    sq += x[i] * x[i];
  }
  s = block_reduce_sum256(s, scratch);
  sq = block_reduce_sum256(sq, scratch);
  float mean = s * (1.f / D);
  float inv = rsqrtf(sq * (1.f / D) - mean * mean + EPS);
  float y[4];
  s = 0.f;
  sq = 0.f;
#pragma unroll
  for (int i = 0; i < 4; i++) {
    int d = tid + i * 256;
    y[i] = (x[i] - mean) * inv * tg[d] + tb[d];
    s += y[i];
    sq += y[i] * y[i];
  }
  s = block_reduce_sum256(s, scratch);
  sq = block_reduce_sum256(sq, scratch);
  float mean2 = s * (1.f / D);
  float inv2 = rsqrtf(sq * (1.f / D) - mean2 * mean2 + EPS);
#pragma unroll
  for (int i = 0; i < 4; i++) {
    int d = tid + i * 256;
    yf[d] = (y[i] - mean2) * inv2 * dg[d] + db[d];
  }
  __syncthreads();
  for (int oo = 0; oo < NOUT; oo++) {
    float part = 0.f;
    for (int d = tid; d < D; d += 256) part += yf[d] * ow[(size_t)oo * D + d];
    part = block_reduce_sum256(part, scratch);
    if (tid == 0) out[b * NOUT + oo] = part + ob[oo];
  }
}

extern "C" void kernel_launch(void* const* d_in, const int* in_sizes, int n_in,
                              void* d_out, int out_size, void* d_ws,
                              size_t ws_size, hipStream_t stream) {
  const float* x = (const float*)d_in[0];
  const float* ln1_g = (const float*)d_in[1];
  const float* ln1_b = (const float*)d_in[2];
  const float* qw = (const float*)d_in[3];
  const float* qb_ = (const float*)d_in[4];
  const float* kw = (const float*)d_in[5];
  const float* kb_ = (const float*)d_in[6];
  const float* vw = (const float*)d_in[7];
  const float* vb_ = (const float*)d_in[8];
  const float* ow = (const float*)d_in[9];
  const float* ob = (const float*)d_in[10];
  const float* ln2_g = (const float*)d_in[11];
  const float* ln2_b = (const float*)d_in[12];
  const float* selw = (const float*)d_in[13];
  const float* w1 = (const float*)d_in[14];
  const float* w2 = (const float*)d_in[15];
  const float* lntg = (const float*)d_in[16];
  const float* lntb = (const float*)d_in[17];
  const float* lndg = (const float*)d_in[18];
  const float* lndb = (const float*)d_in[19];
  const float* inw = (const float*)d_in[20];
  const float* inb = (const float*)d_in[21];
  const float* outw = (const float*)d_in[22];
  const float* outb = (const float*)d_in[23];
  float* out = (float*)d_out;

  // ---- workspace layout ----
  float* h = (float*)d_ws;                      // TOK*D f32
  float* xn = h + (size_t)TOK * D;              // TOK*D f32
  float* gm = xn + (size_t)TOK * D;             // TOK*E f32
  float* qkvbias = gm + (size_t)TOK * E;        // 3*D f32
  __bf16* xnb = (__bf16*)(qkvbias + 3 * D);     // TOK*D
  __bf16* qkvbf = xnb + (size_t)TOK * D;        // 3*TOK*D
  __bf16* obf = qkvbf + (size_t)3 * TOK * D;    // TOK*D
  __bf16* midb = obf + (size_t)TOK * D;         // TOK*E*EH
  __bf16* qkvt = midb + (size_t)TOK * E * EH;   // 3*D*D
  __bf16* owt = qkvt + (size_t)3 * D * D;       // D*D
  __bf16* w1t = owt + (size_t)D * D;            // E*EH*D
  __bf16* w2t = w1t + (size_t)E * EH * D;       // D*(E*EH)

  __bf16* qbf = qkvbf;
  __bf16* kbf = qkvbf + (size_t)TOK * D;
  __bf16* vbf = qkvbf + (size_t)2 * TOK * D;

  // input proj: h = x @ in_w^T + in_b (fp32, K=32)
  gemm_kernel<<<dim3(D / BN, TOK / BM), 256, 0, stream>>>(x, inw, inb, h, TOK,
                                                          D, DIN);
  for (int l = 0; l < LNUM; l++) {
    ln_kernel<<<TOK, 256, 0, stream>>>(h, ln1_g + l * D, ln1_b + l * D, xn,
                                       xnb);
    transpose_cvt<<<dim3(D / 32, D / 32, 1), dim3(32, 8), 0, stream>>>(
        qw + (size_t)l * D * D, 0, qkvt, 0, D, D, D);
    transpose_cvt<<<dim3(D / 32, D / 32, 1), dim3(32, 8), 0, stream>>>(
        kw + (size_t)l * D * D, 0, qkvt + (size_t)D * D, 0, D, D, D);
    transpose_cvt<<<dim3(D / 32, D / 32, 1), dim3(32, 8), 0, stream>>>(
        vw + (size_t)l * D * D, 0, qkvt + (size_t)2 * D * D, 0, D, D, D);
    copy3<<<12, 256, 0, stream>>>(qb_ + l * D, kb_ + l * D, vb_ + l * D,
                                  qkvbias);
    // q,k,v = xn @ {q,k,v}w + bias -> bf16 (z = 0..2)
    mfma_gemm<<<dim3(D / 128, TOK / 128, 3), 256, 0, stream>>>(
        xnb, D, 0, qkvt, (long long)D * D, qkvbias, D, nullptr, qkvbf, D,
        (long long)TOK * D, nullptr, 0, D, 0, 0);
    rope_kernel_bf<<<dim3(S, B), 256, 0, stream>>>(qbf, kbf);
    attn_mfma<<<dim3(S / 64, H, B), 256, 0, stream>>>(qbf, kbf, vbf, obf);
    // h += o @ ow^T + ob
    cvt_kernel<<<512, 256, 0, stream>>>(ow + (size_t)l * D * D, owt, D * D);
    mfma_gemm<<<dim3(D / 128, TOK / 128, 1), 256, 0, stream>>>(
        obf, D, 0, owt, 0, ob + l * D, 0, h, nullptr, D, 0, nullptr, 0, D, 1,
        0);
    ln_kernel<<<TOK, 256, 0, stream>>>(h, ln2_g + l * D, ln2_b + l * D, xn,
                                       xnb);
    gate_kernel<<<TOK, 256, 0, stream>>>(xn, selw + (size_t)l * D * E, gm);
    transpose_cvt<<<dim3(EH / 32, D / 32, E), dim3(32, 8), 0, stream>>>(
        w1 + (size_t)l * E * D * EH, (long long)D * EH, w1t, (long long)EH * D,
        D, EH, D);
    mfma_gemm<<<dim3(EH / 128, TOK / 128, E), 256, 0, stream>>>(
        xnb, D, 0, w1t, (long long)EH * D, nullptr, 0, nullptr, midb, E * EH,
        EH, gm, E, D, 0, 1);
    transpose_cvt<<<dim3(D / 32, EH / 32, E), dim3(32, 8), 0, stream>>>(
        w2 + (size_t)l * E * EH * D, (long long)EH * D, w2t, EH, EH, D, E * EH);
    mfma_gemm<<<dim3(D / 128, TOK / 128, 1), 256, 0, stream>>>(
        midb, E * EH, 0, w2t, 0, nullptr, 0, h, nullptr, D, 0, nullptr, 0,
        E * EH, 1, 0);
  }
  final_kernel<<<B, 256, 0, stream>>>(h, lntg, lntb, lndg, lndb, outw, outb,
                                      out);
}

// Round 4
// 745.791 us; speedup vs baseline: 11.8421x; 1.3332x over previous
//
#include <hip/hip_runtime.h>

// MoEUT time-series decoder, round 4.
// - mfma_gemm templated 64xBN tiles (waves 2x2) for 2-4 blocks/CU on the
//   small per-layer GEMM shapes (QKV BN=128; Oproj/w1/w2 BN=64).
// - XOR swizzle on LDS staging/fragment reads: 8-way bank conflicts -> 2-way.
// - ln2+gate fused; LN writes bf16 only (fp32 xn removed).

#define LNUM 3
#define D 1024
#define H 16
#define HD 64
#define E 8
#define EH 256
#define B 2
#define S 1024
#define DIN 32
#define NOUT 8
#define EPS 1e-5f
#define TOK (B * S)

typedef __bf16 bf16x8 __attribute__((ext_vector_type(8)));
typedef __bf16 bf16x4 __attribute__((ext_vector_type(4)));
typedef float fx4 __attribute__((ext_vector_type(4)));

// ---------------- reductions ----------------
__device__ inline float block_reduce_sum256(float v, float* scratch) {
  int lane = threadIdx.x & 63, wv = threadIdx.x >> 6;
#pragma unroll
  for (int off = 32; off; off >>= 1) v += __shfl_down(v, off);
  __syncthreads();
  if (lane == 0) scratch[wv] = v;
  __syncthreads();
  return scratch[0] + scratch[1] + scratch[2] + scratch[3];
}

// ---------------- LayerNorm -> bf16 only ----------------
__global__ __launch_bounds__(256) void ln_bf_kernel(
    const float* __restrict__ in, const float* __restrict__ g,
    const float* __restrict__ bta, __bf16* __restrict__ outb) {
  int token = blockIdx.x;
  int tid = threadIdx.x;
  const float* p = in + (size_t)token * D;
  __shared__ float scratch[4];
  float x[4];
  float s = 0.f, sq = 0.f;
#pragma unroll
  for (int i = 0; i < 4; i++) {
    x[i] = p[tid + i * 256];
    s += x[i];
    sq += x[i] * x[i];
  }
  s = block_reduce_sum256(s, scratch);
  sq = block_reduce_sum256(sq, scratch);
  float mean = s * (1.f / D);
  float inv = rsqrtf(sq * (1.f / D) - mean * mean + EPS);
  __bf16* obp = outb + (size_t)token * D;
#pragma unroll
  for (int i = 0; i < 4; i++) {
    int d = tid + i * 256;
    obp[d] = (__bf16)((x[i] - mean) * inv * g[d] + bta[d]);
  }
}

// ---------------- LayerNorm + sigmoid gate top-2 (fused) ----------------
__global__ __launch_bounds__(256) void ln_gate_kernel(
    const float* __restrict__ in, const float* __restrict__ g,
    const float* __restrict__ bta, const float* __restrict__ selw,
    __bf16* __restrict__ outb, float* __restrict__ gm) {
  int token = blockIdx.x;
  int tid = threadIdx.x;
  const float* p = in + (size_t)token * D;
  __shared__ float scratch[4];
  float x[4];
  float s = 0.f, sq = 0.f;
#pragma unroll
  for (int i = 0; i < 4; i++) {
    x[i] = p[tid + i * 256];
    s += x[i];
    sq += x[i] * x[i];
  }
  s = block_reduce_sum256(s, scratch);
  sq = block_reduce_sum256(sq, scratch);
  float mean = s * (1.f / D);
  float inv = rsqrtf(sq * (1.f / D) - mean * mean + EPS);
  __bf16* obp = outb + (size_t)token * D;
  float ge[E];
#pragma unroll
  for (int e = 0; e < E; e++) ge[e] = 0.f;
#pragma unroll
  for (int i = 0; i < 4; i++) {
    int d = tid + i * 256;
    float y = (x[i] - mean) * inv * g[d] + bta[d];
    obp[d] = (__bf16)y;
#pragma unroll
    for (int e = 0; e < E; e++) ge[e] += y * selw[d * E + e];
  }
  __shared__ float red[4][E];
  int lane = tid & 63, wv = tid >> 6;
#pragma unroll
  for (int e = 0; e < E; e++) {
    float vv = ge[e];
#pragma unroll
    for (int off = 32; off; off >>= 1) vv += __shfl_down(vv, off);
    if (lane == 0) red[wv][e] = vv;
  }
  __syncthreads();
  if (tid == 0) {
    float gg[E];
    for (int e = 0; e < E; e++) {
      float sv = red[0][e] + red[1][e] + red[2][e] + red[3][e];
      gg[e] = 1.f / (1.f + __expf(-sv));
    }
    int i0 = 0;
    for (int e = 1; e < E; e++)
      if (gg[e] > gg[i0]) i0 = e;
    int i1 = -1;
    for (int e = 0; e < E; e++) {
      if (e == i0) continue;
      if (i1 < 0 || gg[e] > gg[i1]) i1 = e;
    }
    float mm[E];
    for (int e = 0; e < E; e++) mm[e] = 0.f;
    mm[i0] = gg[i0];
    mm[i1] = gg[i1];
    for (int e = 0; e < E; e++) gm[(size_t)token * E + e] = mm[e];
  }
}

// ---------------- fp32 tiled GEMM (input projection, K=32) ----------
#define BM 64
#define BKT 16
__global__ __launch_bounds__(256) void gemm_kernel(
    const float* __restrict__ A, const float* __restrict__ Bw,
    const float* __restrict__ bias, float* __restrict__ C, int M, int N,
    int Kd) {
  __shared__ float As[BKT][BM + 1];
  __shared__ float Bs[BKT][BM + 1];
  int bm = blockIdx.y * BM, bn = blockIdx.x * BM;
  int tid = threadIdx.x;
  int tx = tid & 15, ty = tid >> 4;
  float acc[4][4] = {};
  for (int k0 = 0; k0 < Kd; k0 += BKT) {
#pragma unroll
    for (int j = 0; j < 4; j++) {
      int i = tid + j * 256;
      int r = i >> 4, c = i & 15;
      As[c][r] = A[(size_t)(bm + r) * Kd + k0 + c];
    }
#pragma unroll
    for (int j = 0; j < 4; j++) {
      int i = tid + j * 256;
      int n = i >> 4, c = i & 15;
      Bs[c][n] = Bw[(size_t)(bn + n) * Kd + k0 + c];
    }
    __syncthreads();
#pragma unroll
    for (int kk = 0; kk < BKT; kk++) {
      float a[4], bb[4];
#pragma unroll
      for (int i2 = 0; i2 < 4; i2++) a[i2] = As[kk][ty * 4 + i2];
#pragma unroll
      for (int i2 = 0; i2 < 4; i2++) bb[i2] = Bs[kk][tx * 4 + i2];
#pragma unroll
      for (int i2 = 0; i2 < 4; i2++)
#pragma unroll
        for (int j2 = 0; j2 < 4; j2++) acc[i2][j2] += a[i2] * bb[j2];
    }
    __syncthreads();
  }
#pragma unroll
  for (int i2 = 0; i2 < 4; i2++) {
    int row = bm + ty * 4 + i2;
#pragma unroll
    for (int j2 = 0; j2 < 4; j2++) {
      int col = bn + tx * 4 + j2;
      C[(size_t)row * N + col] = acc[i2][j2] + bias[col];
    }
  }
}

// ---------------- bf16 MFMA GEMM, 64xBN tile, BK=32, XOR-swizzled LDS ----
// C[M,N] = epi(A[M,K] @ Bt[N,K]^T), z-batched. NI = BN/32 (2 or 4).
template <int NI>
__global__ __launch_bounds__(256) void mfma_gemm(
    const __bf16* __restrict__ A, int lda, long long aZ,
    const __bf16* __restrict__ Bt, long long bZ, const float* __restrict__ bias,
    long long biasZ, float* __restrict__ C, __bf16* __restrict__ Cbf, int ldc,
    long long cZ, const float* __restrict__ rowScale, int rsLd, int K,
    int accum, int relu) {
  constexpr int BN = NI * 32;
  __shared__ __bf16 As[64 * 32];
  __shared__ __bf16 Bs[BN * 32];
  int z = blockIdx.z;
  int bm = blockIdx.y * 64, bn = blockIdx.x * BN;
  int tid = threadIdx.x, lane = tid & 63, wv = tid >> 6;
  int wr = wv >> 1, wc = wv & 1;
  int half = lane >> 4, mrow = lane & 15;
  const __bf16* Ab = A + (size_t)z * aZ + (size_t)bm * lda;
  const __bf16* Bb = Bt + (size_t)z * bZ + (size_t)bn * K;
  fx4 acc[2][NI] = {};
  // precompute swizzled fragment slots
  int aslot[2], bslot[NI];
#pragma unroll
  for (int i = 0; i < 2; i++) {
    int row = wr * 32 + i * 16 + mrow;
    aslot[i] = row * 4 + (half ^ ((row >> 1) & 3));
  }
#pragma unroll
  for (int j = 0; j < NI; j++) {
    int row = wc * (NI * 16) + j * 16 + mrow;
    bslot[j] = row * 4 + (half ^ ((row >> 1) & 3));
  }
  for (int k0 = 0; k0 < K; k0 += 32) {
    {
      int c = tid;  // 256 A-chunks
      int row = c >> 2;
      int kc = (((c & 3) ^ ((row >> 1) & 3)) << 3);
      __builtin_amdgcn_global_load_lds(
          (const __attribute__((address_space(1))) void*)(Ab +
                                                          (size_t)row * lda +
                                                          k0 + kc),
          (__attribute__((address_space(3))) void*)(As + c * 8), 16, 0, 0);
    }
#pragma unroll
    for (int it = 0; it < NI / 2; it++) {
      int c = tid + it * 256;
      int row = c >> 2;
      int kc = (((c & 3) ^ ((row >> 1) & 3)) << 3);
      __builtin_amdgcn_global_load_lds(
          (const __attribute__((address_space(1))) void*)(Bb + (size_t)row * K +
                                                          k0 + kc),
          (__attribute__((address_space(3))) void*)(Bs + c * 8), 16, 0, 0);
    }
    __syncthreads();
    bf16x8 af[2], bfr[NI];
#pragma unroll
    for (int i = 0; i < 2; i++) af[i] = *(const bf16x8*)(As + aslot[i] * 8);
#pragma unroll
    for (int j = 0; j < NI; j++) bfr[j] = *(const bf16x8*)(Bs + bslot[j] * 8);
#pragma unroll
    for (int i = 0; i < 2; i++)
#pragma unroll
      for (int j = 0; j < NI; j++)
        acc[i][j] = __builtin_amdgcn_mfma_f32_16x16x32_bf16(af[i], bfr[j],
                                                            acc[i][j], 0, 0, 0);
    __syncthreads();
  }
#pragma unroll
  for (int i = 0; i < 2; i++) {
#pragma unroll
    for (int r = 0; r < 4; r++) {
      int row = bm + wr * 32 + i * 16 + half * 4 + r;
      float rs = rowScale ? rowScale[(size_t)row * rsLd + z] : 1.f;
#pragma unroll
      for (int j = 0; j < NI; j++) {
        int col = bn + wc * (NI * 16) + j * 16 + mrow;
        float val = acc[i][j][r];
        if (bias) val += bias[(size_t)z * biasZ + col];
        if (relu) val = fmaxf(val, 0.f);
        val *= rs;
        size_t addr = (size_t)z * cZ + (size_t)row * ldc + col;
        if (Cbf)
          Cbf[addr] = (__bf16)val;
        else if (accum)
          C[addr] += val;
        else
          C[addr] = val;
      }
    }
  }
}

// ---------------- fp32 -> bf16 transpose+convert -------------------------
__global__ void transpose_cvt(const float* __restrict__ src, long long srcZ,
                              __bf16* __restrict__ dst, long long dstZ, int R,
                              int C, int dstLd) {
  __shared__ float t[32][33];
  int r0 = blockIdx.y * 32, c0 = blockIdx.x * 32;
  int z = blockIdx.z;
  src += (size_t)z * srcZ;
  int tx = threadIdx.x, ty = threadIdx.y;
#pragma unroll
  for (int i = 0; i < 4; i++) {
    int r = r0 + ty + i * 8;
    t[ty + i * 8][tx] = src[(size_t)r * C + c0 + tx];
  }
  __syncthreads();
#pragma unroll
  for (int i = 0; i < 4; i++) {
    int c = c0 + ty + i * 8;
    dst[(size_t)c * dstLd + (size_t)z * dstZ + r0 + tx] =
        (__bf16)t[tx][ty + i * 8];
  }
}

__global__ void cvt_kernel(const float* __restrict__ s, __bf16* __restrict__ d,
                           int n) {
  for (int i = blockIdx.x * 256 + threadIdx.x; i < n; i += gridDim.x * 256)
    d[i] = (__bf16)s[i];
}

__global__ void copy3(const float* __restrict__ a, const float* __restrict__ b,
                      const float* __restrict__ c, float* __restrict__ dst) {
  int i = blockIdx.x * 256 + threadIdx.x;
  if (i < D)
    dst[i] = a[i];
  else if (i < 2 * D)
    dst[i] = b[i - D];
  else if (i < 3 * D)
    dst[i] = c[i - 2 * D];
}

// ---------------- RoPE in-place on bf16 q,k ----------------
__global__ __launch_bounds__(256) void rope_kernel_bf(__bf16* __restrict__ q,
                                                      __bf16* __restrict__ k) {
  int s = blockIdx.x, b = blockIdx.y;
  int tid = threadIdx.x;
  for (int i = tid; i < H * (HD / 2); i += 256) {
    int hh = i >> 5, j = i & 31;
    float inv = exp2f(-(2.f * j / HD) * 13.2877123795494f);
    float ang = (float)s * inv;
    float c = cosf(ang), sn = sinf(ang);
    size_t base = ((size_t)(b * S + s)) * D + hh * HD;
    float a0 = (float)q[base + j], a1 = (float)q[base + j + 32];
    q[base + j] = (__bf16)(a0 * c - a1 * sn);
    q[base + j + 32] = (__bf16)(a1 * c + a0 * sn);
    float b0 = (float)k[base + j], b1 = (float)k[base + j + 32];
    k[base + j] = (__bf16)(b0 * c - b1 * sn);
    k[base + j + 32] = (__bf16)(b1 * c + b0 * sn);
  }
}

// ---------------- bf16 MFMA flash attention ----------------
#define KT_LD 72
#define VT_LD 68
#define P_LD 72
__global__ __launch_bounds__(256) void attn_mfma(const __bf16* __restrict__ qb,
                                                 const __bf16* __restrict__ kb,
                                                 const __bf16* __restrict__ vb,
                                                 __bf16* __restrict__ obf) {
  __shared__ __bf16 Kt[64 * KT_LD];
  __shared__ __bf16 Vt[HD * VT_LD];
  __shared__ __bf16 Pb[64 * P_LD];
  int q0 = blockIdx.x * 64, hh = blockIdx.y, b = blockIdx.z;
  int tid = threadIdx.x, lane = tid & 63, wv = tid >> 6;
  int col = lane & 15, half = lane >> 4;
  const size_t headoff = (size_t)hh * HD;
  const float scale = 0.125f;

  const __bf16* qbase =
      qb + ((size_t)(b * S + q0 + wv * 16 + col)) * D + headoff;
  bf16x8 qf0 = *(const bf16x8*)(qbase + half * 8);
  bf16x8 qf1 = *(const bf16x8*)(qbase + 32 + half * 8);

  fx4 Oacc[4] = {};
  float m_i[4] = {-1e30f, -1e30f, -1e30f, -1e30f};
  float l_i[4] = {0.f, 0.f, 0.f, 0.f};

  for (int t0 = 0; t0 < S; t0 += 64) {
    __syncthreads();
#pragma unroll
    for (int it = 0; it < 2; it++) {
      int c = tid + it * 256;
      int row = c >> 3, off = (c & 7) * 8;
      *(bf16x8*)(Kt + row * KT_LD + off) =
          *(const bf16x8*)(kb + ((size_t)(b * S + t0 + row)) * D + headoff +
                           off);
    }
    {
      int dgroup = tid & 7, tpair = tid >> 3;
      int t = tpair * 2;
      bf16x8 v0 = *(const bf16x8*)(vb + ((size_t)(b * S + t0 + t)) * D +
                                   headoff + dgroup * 8);
      bf16x8 v1 = *(const bf16x8*)(vb + ((size_t)(b * S + t0 + t + 1)) * D +
                                   headoff + dgroup * 8);
#pragma unroll
      for (int j = 0; j < 8; j++) {
        __bf16* p = Vt + (dgroup * 8 + j) * VT_LD + t;
        p[0] = v0[j];
        p[1] = v1[j];
      }
    }
    __syncthreads();

    fx4 sacc[4] = {};
#pragma unroll
    for (int n = 0; n < 4; n++) {
      bf16x8 b0 = *(const bf16x8*)(Kt + (n * 16 + col) * KT_LD + half * 8);
      bf16x8 b1 = *(const bf16x8*)(Kt + (n * 16 + col) * KT_LD + 32 + half * 8);
      sacc[n] =
          __builtin_amdgcn_mfma_f32_16x16x32_bf16(qf0, b0, sacc[n], 0, 0, 0);
      sacc[n] =
          __builtin_amdgcn_mfma_f32_16x16x32_bf16(qf1, b1, sacc[n], 0, 0, 0);
    }
#pragma unroll
    for (int r = 0; r < 4; r++) {
      float mx =
          fmaxf(fmaxf(sacc[0][r], sacc[1][r]), fmaxf(sacc[2][r], sacc[3][r]));
#pragma unroll
      for (int msk = 1; msk < 16; msk <<= 1)
        mx = fmaxf(mx, __shfl_xor(mx, msk));
      float nm = fmaxf(m_i[r], mx * scale);
      float alpha = __expf(m_i[r] - nm);
      m_i[r] = nm;
      l_i[r] *= alpha;
#pragma unroll
      for (int n = 0; n < 4; n++) Oacc[n][r] *= alpha;
      float part = 0.f;
      int prow = (wv * 16 + half * 4 + r) * P_LD;
#pragma unroll
      for (int n = 0; n < 4; n++) {
        float p = __expf(sacc[n][r] * scale - nm);
        part += p;
        Pb[prow + n * 16 + col] = (__bf16)p;
      }
#pragma unroll
      for (int msk = 1; msk < 16; msk <<= 1) part += __shfl_xor(part, msk);
      l_i[r] += part;
    }
#pragma unroll
    for (int k0 = 0; k0 < 2; k0++) {
      bf16x8 af =
          *(const bf16x8*)(Pb + (wv * 16 + col) * P_LD + k0 * 32 + half * 8);
#pragma unroll
      for (int n = 0; n < 4; n++) {
        const __bf16* vp = Vt + (n * 16 + col) * VT_LD + k0 * 32 + half * 8;
        bf16x4 lo = *(const bf16x4*)vp;
        bf16x4 hi = *(const bf16x4*)(vp + 4);
        bf16x8 bfv;
#pragma unroll
        for (int j = 0; j < 4; j++) {
          bfv[j] = lo[j];
          bfv[4 + j] = hi[j];
        }
        Oacc[n] =
            __builtin_amdgcn_mfma_f32_16x16x32_bf16(af, bfv, Oacc[n], 0, 0, 0);
      }
    }
  }
#pragma unroll
  for (int r = 0; r < 4; r++) {
    float inv = 1.f / l_i[r];
    int row = q0 + wv * 16 + half * 4 + r;
    __bf16* op = obf + ((size_t)(b * S + row)) * D + headoff;
#pragma unroll
    for (int n = 0; n < 4; n++) op[n * 16 + col] = (__bf16)(Oacc[n][r] * inv);
  }
}

// ---------------- final head: last token only ----------------
__global__ __launch_bounds__(256) void final_kernel(
    const float* __restrict__ h, const float* __restrict__ tg,
    const float* __restrict__ tb, const float* __restrict__ dg,
    const float* __restrict__ db, const float* __restrict__ ow,
    const float* __restrict__ ob, float* __restrict__ out) {
  int b = blockIdx.x;
  int tid = threadIdx.x;
  __shared__ float scratch[4];
  __shared__ float yf[D];
  const float* p = h + ((size_t)(b * S + (S - 1))) * D;
  float x[4];
  float s = 0.f, sq = 0.f;
#pragma unroll
  for (int i = 0; i < 4; i++) {
    x[i] = p[tid + i * 256];
    s += x[i];
    sq += x[i] * x[i];
  }
  s = block_reduce_sum256(s, scratch);
  sq = block_reduce_sum256(sq, scratch);
  float mean = s * (1.f / D);
  float inv = rsqrtf(sq * (1.f / D) - mean * mean + EPS);
  float y[4];
  s = 0.f;
  sq = 0.f;
#pragma unroll
  for (int i = 0; i < 4; i++) {
    int d = tid + i * 256;
    y[i] = (x[i] - mean) * inv * tg[d] + tb[d];
    s += y[i];
    sq += y[i] * y[i];
  }
  s = block_reduce_sum256(s, scratch);
  sq = block_reduce_sum256(sq, scratch);
  float mean2 = s * (1.f / D);
  float inv2 = rsqrtf(sq * (1.f / D) - mean2 * mean2 + EPS);
#pragma unroll
  for (int i = 0; i < 4; i++) {
    int d = tid + i * 256;
    yf[d] = (y[i] - mean2) * inv2 * dg[d] + db[d];
  }
  __syncthreads();
  for (int oo = 0; oo < NOUT; oo++) {
    float part = 0.f;
    for (int d = tid; d < D; d += 256) part += yf[d] * ow[(size_t)oo * D + d];
    part = block_reduce_sum256(part, scratch);
    if (tid == 0) out[b * NOUT + oo] = part + ob[oo];
  }
}

extern "C" void kernel_launch(void* const* d_in, const int* in_sizes, int n_in,
                              void* d_out, int out_size, void* d_ws,
                              size_t ws_size, hipStream_t stream) {
  const float* x = (const float*)d_in[0];
  const float* ln1_g = (const float*)d_in[1];
  const float* ln1_b = (const float*)d_in[2];
  const float* qw = (const float*)d_in[3];
  const float* qb_ = (const float*)d_in[4];
  const float* kw = (const float*)d_in[5];
  const float* kb_ = (const float*)d_in[6];
  const float* vw = (const float*)d_in[7];
  const float* vb_ = (const float*)d_in[8];
  const float* ow = (const float*)d_in[9];
  const float* ob = (const float*)d_in[10];
  const float* ln2_g = (const float*)d_in[11];
  const float* ln2_b = (const float*)d_in[12];
  const float* selw = (const float*)d_in[13];
  const float* w1 = (const float*)d_in[14];
  const float* w2 = (const float*)d_in[15];
  const float* lntg = (const float*)d_in[16];
  const float* lntb = (const float*)d_in[17];
  const float* lndg = (const float*)d_in[18];
  const float* lndb = (const float*)d_in[19];
  const float* inw = (const float*)d_in[20];
  const float* inb = (const float*)d_in[21];
  const float* outw = (const float*)d_in[22];
  const float* outb = (const float*)d_in[23];
  float* out = (float*)d_out;

  // ---- workspace layout ----
  float* h = (float*)d_ws;                     // TOK*D f32
  float* gm = h + (size_t)TOK * D;             // TOK*E f32
  float* qkvbias = gm + (size_t)TOK * E;       // 3*D f32
  __bf16* xnb = (__bf16*)(qkvbias + 3 * D);    // TOK*D
  __bf16* qkvbf = xnb + (size_t)TOK * D;       // 3*TOK*D
  __bf16* obf = qkvbf + (size_t)3 * TOK * D;   // TOK*D
  __bf16* midb = obf + (size_t)TOK * D;        // TOK*E*EH
  __bf16* qkvt = midb + (size_t)TOK * E * EH;  // 3*D*D
  __bf16* owt = qkvt + (size_t)3 * D * D;      // D*D
  __bf16* w1t = owt + (size_t)D * D;           // E*EH*D
  __bf16* w2t = w1t + (size_t)E * EH * D;      // D*(E*EH)

  __bf16* qbf = qkvbf;
  __bf16* kbf = qkvbf + (size_t)TOK * D;
  __bf16* vbf = qkvbf + (size_t)2 * TOK * D;

  gemm_kernel<<<dim3(D / 64, TOK / 64), 256, 0, stream>>>(x, inw, inb, h, TOK,
                                                          D, DIN);
  for (int l = 0; l < LNUM; l++) {
    ln_bf_kernel<<<TOK, 256, 0, stream>>>(h, ln1_g + l * D, ln1_b + l * D, xnb);
    transpose_cvt<<<dim3(D / 32, D / 32, 1), dim3(32, 8), 0, stream>>>(
        qw + (size_t)l * D * D, 0, qkvt, 0, D, D, D);
    transpose_cvt<<<dim3(D / 32, D / 32, 1), dim3(32, 8), 0, stream>>>(
        kw + (size_t)l * D * D, 0, qkvt + (size_t)D * D, 0, D, D, D);
    transpose_cvt<<<dim3(D / 32, D / 32, 1), dim3(32, 8), 0, stream>>>(
        vw + (size_t)l * D * D, 0, qkvt + (size_t)2 * D * D, 0, D, D, D);
    copy3<<<12, 256, 0, stream>>>(qb_ + l * D, kb_ + l * D, vb_ + l * D,
                                  qkvbias);
    // q,k,v = xn @ {q,k,v}w + bias -> bf16 (z=0..2), 64x128 tile
    mfma_gemm<4><<<dim3(D / 128, TOK / 64, 3), 256, 0, stream>>>(
        xnb, D, 0, qkvt, (long long)D * D, qkvbias, D, nullptr, qkvbf, D,
        (long long)TOK * D, nullptr, 0, D, 0, 0);
    rope_kernel_bf<<<dim3(S, B), 256, 0, stream>>>(qbf, kbf);
    attn_mfma<<<dim3(S / 64, H, B), 256, 0, stream>>>(qbf, kbf, vbf, obf);
    // h += o @ ow^T + ob, 64x64 tile
    cvt_kernel<<<512, 256, 0, stream>>>(ow + (size_t)l * D * D, owt, D * D);
    mfma_gemm<2><<<dim3(D / 64, TOK / 64, 1), 256, 0, stream>>>(
        obf, D, 0, owt, 0, ob + l * D, 0, h, nullptr, D, 0, nullptr, 0, D, 1,
        0);
    ln_gate_kernel<<<TOK, 256, 0, stream>>>(h, ln2_g + l * D, ln2_b + l * D,
                                            selw + (size_t)l * D * E, xnb, gm);
    transpose_cvt<<<dim3(EH / 32, D / 32, E), dim3(32, 8), 0, stream>>>(
        w1 + (size_t)l * E * D * EH, (long long)D * EH, w1t, (long long)EH * D,
        D, EH, D);
    // mid[t][e*EH+eh] = relu(xn @ w1[e]) * gate[t][e], 64x64 tile, z=8
    mfma_gemm<2><<<dim3(EH / 64, TOK / 64, E), 256, 0, stream>>>(
        xnb, D, 0, w1t, (long long)EH * D, nullptr, 0, nullptr, midb, E * EH,
        EH, gm, E, D, 0, 1);
    transpose_cvt<<<dim3(D / 32, EH / 32, E), dim3(32, 8), 0, stream>>>(
        w2 + (size_t)l * E * EH * D, (long long)EH * D, w2t, EH, EH, D, E * EH);
    // h += mid @ w2stacked (K = E*EH = 2048), 64x64 tile
    mfma_gemm<2><<<dim3(D / 64, TOK / 64, 1), 256, 0, stream>>>(
        midb, E * EH, 0, w2t, 0, nullptr, 0, h, nullptr, D, 0, nullptr, 0,
        E * EH, 1, 0);
  }
  final_kernel<<<B, 256, 0, stream>>>(h, lntg, lntb, lndg, lndb, outw, outb,
                                      out);
}

// Round 5
// 692.950 us; speedup vs baseline: 12.7451x; 1.0763x over previous
//
#include <hip/hip_runtime.h>

// MoEUT time-series decoder, round 5.
// - attn: Kt via swizzled global_load_lds (conflict-free b128 reads),
//   Vt packed-b32 transpose writes + union b64 reads, RoPE hoisted out.
// - RoPE fused into QKV GEMM epilogue (fp32, pre-rounding).
// - weight prep batched cross-layer into 7 launches at start.

#define LNUM 3
#define D 1024
#define H 16
#define HD 64
#define E 8
#define EH 256
#define B 2
#define S 1024
#define DIN 32
#define NOUT 8
#define EPS 1e-5f
#define TOK (B * S)

typedef __bf16 bf16x8 __attribute__((ext_vector_type(8)));
typedef __bf16 bf16x4 __attribute__((ext_vector_type(4)));
typedef float fx4 __attribute__((ext_vector_type(4)));

// ---------------- reductions ----------------
__device__ inline float block_reduce_sum256(float v, float* scratch) {
  int lane = threadIdx.x & 63, wv = threadIdx.x >> 6;
#pragma unroll
  for (int off = 32; off; off >>= 1) v += __shfl_down(v, off);
  __syncthreads();
  if (lane == 0) scratch[wv] = v;
  __syncthreads();
  return scratch[0] + scratch[1] + scratch[2] + scratch[3];
}

// ---------------- LayerNorm -> bf16 ----------------
__global__ __launch_bounds__(256) void ln_bf_kernel(
    const float* __restrict__ in, const float* __restrict__ g,
    const float* __restrict__ bta, __bf16* __restrict__ outb) {
  int token = blockIdx.x;
  int tid = threadIdx.x;
  const float* p = in + (size_t)token * D;
  __shared__ float scratch[4];
  float x[4];
  float s = 0.f, sq = 0.f;
#pragma unroll
  for (int i = 0; i < 4; i++) {
    x[i] = p[tid + i * 256];
    s += x[i];
    sq += x[i] * x[i];
  }
  s = block_reduce_sum256(s, scratch);
  sq = block_reduce_sum256(sq, scratch);
  float mean = s * (1.f / D);
  float inv = rsqrtf(sq * (1.f / D) - mean * mean + EPS);
  __bf16* obp = outb + (size_t)token * D;
#pragma unroll
  for (int i = 0; i < 4; i++) {
    int d = tid + i * 256;
    obp[d] = (__bf16)((x[i] - mean) * inv * g[d] + bta[d]);
  }
}

// ---------------- LayerNorm + sigmoid gate top-2 (fused) ----------------
__global__ __launch_bounds__(256) void ln_gate_kernel(
    const float* __restrict__ in, const float* __restrict__ g,
    const float* __restrict__ bta, const float* __restrict__ selw,
    __bf16* __restrict__ outb, float* __restrict__ gm) {
  int token = blockIdx.x;
  int tid = threadIdx.x;
  const float* p = in + (size_t)token * D;
  __shared__ float scratch[4];
  float x[4];
  float s = 0.f, sq = 0.f;
#pragma unroll
  for (int i = 0; i < 4; i++) {
    x[i] = p[tid + i * 256];
    s += x[i];
    sq += x[i] * x[i];
  }
  s = block_reduce_sum256(s, scratch);
  sq = block_reduce_sum256(sq, scratch);
  float mean = s * (1.f / D);
  float inv = rsqrtf(sq * (1.f / D) - mean * mean + EPS);
  __bf16* obp = outb + (size_t)token * D;
  float ge[E];
#pragma unroll
  for (int e = 0; e < E; e++) ge[e] = 0.f;
#pragma unroll
  for (int i = 0; i < 4; i++) {
    int d = tid + i * 256;
    float y = (x[i] - mean) * inv * g[d] + bta[d];
    obp[d] = (__bf16)y;
#pragma unroll
    for (int e = 0; e < E; e++) ge[e] += y * selw[d * E + e];
  }
  __shared__ float red[4][E];
  int lane = tid & 63, wv = tid >> 6;
#pragma unroll
  for (int e = 0; e < E; e++) {
    float vv = ge[e];
#pragma unroll
    for (int off = 32; off; off >>= 1) vv += __shfl_down(vv, off);
    if (lane == 0) red[wv][e] = vv;
  }
  __syncthreads();
  if (tid == 0) {
    float gg[E];
    for (int e = 0; e < E; e++) {
      float sv = red[0][e] + red[1][e] + red[2][e] + red[3][e];
      gg[e] = 1.f / (1.f + __expf(-sv));
    }
    int i0 = 0;
    for (int e = 1; e < E; e++)
      if (gg[e] > gg[i0]) i0 = e;
    int i1 = -1;
    for (int e = 0; e < E; e++) {
      if (e == i0) continue;
      if (i1 < 0 || gg[e] > gg[i1]) i1 = e;
    }
    float mm[E];
    for (int e = 0; e < E; e++) mm[e] = 0.f;
    mm[i0] = gg[i0];
    mm[i1] = gg[i1];
    for (int e = 0; e < E; e++) gm[(size_t)token * E + e] = mm[e];
  }
}

// ---------------- fp32 tiled GEMM (input projection, K=32) ----------
#define BM 64
#define BKT 16
__global__ __launch_bounds__(256) void gemm_kernel(
    const float* __restrict__ A, const float* __restrict__ Bw,
    const float* __restrict__ bias, float* __restrict__ C, int M, int N,
    int Kd) {
  __shared__ float As[BKT][BM + 1];
  __shared__ float Bs[BKT][BM + 1];
  int bm = blockIdx.y * BM, bn = blockIdx.x * BM;
  int tid = threadIdx.x;
  int tx = tid & 15, ty = tid >> 4;
  float acc[4][4] = {};
  for (int k0 = 0; k0 < Kd; k0 += BKT) {
#pragma unroll
    for (int j = 0; j < 4; j++) {
      int i = tid + j * 256;
      int r = i >> 4, c = i & 15;
      As[c][r] = A[(size_t)(bm + r) * Kd + k0 + c];
    }
#pragma unroll
    for (int j = 0; j < 4; j++) {
      int i = tid + j * 256;
      int n = i >> 4, c = i & 15;
      Bs[c][n] = Bw[(size_t)(bn + n) * Kd + k0 + c];
    }
    __syncthreads();
#pragma unroll
    for (int kk = 0; kk < BKT; kk++) {
      float a[4], bb[4];
#pragma unroll
      for (int i2 = 0; i2 < 4; i2++) a[i2] = As[kk][ty * 4 + i2];
#pragma unroll
      for (int i2 = 0; i2 < 4; i2++) bb[i2] = Bs[kk][tx * 4 + i2];
#pragma unroll
      for (int i2 = 0; i2 < 4; i2++)
#pragma unroll
        for (int j2 = 0; j2 < 4; j2++) acc[i2][j2] += a[i2] * bb[j2];
    }
    __syncthreads();
  }
#pragma unroll
  for (int i2 = 0; i2 < 4; i2++) {
    int row = bm + ty * 4 + i2;
#pragma unroll
    for (int j2 = 0; j2 < 4; j2++) {
      int col = bn + tx * 4 + j2;
      C[(size_t)row * N + col] = acc[i2][j2] + bias[col];
    }
  }
}

// ---------------- bf16 MFMA GEMM, 64xBN tile, BK=32, XOR-swizzled LDS ----
// rope!=0: apply RoPE to (col, col+32) pairs within 64-col blocks (z<2 only).
template <int NI>
__global__ __launch_bounds__(256) void mfma_gemm(
    const __bf16* __restrict__ A, int lda, long long aZ,
    const __bf16* __restrict__ Bt, long long bZ, const float* __restrict__ bias,
    long long biasZ, float* __restrict__ C, __bf16* __restrict__ Cbf, int ldc,
    long long cZ, const float* __restrict__ rowScale, int rsLd, int K,
    int accum, int relu, int rope) {
  constexpr int BN = NI * 32;
  __shared__ __bf16 As[64 * 32];
  __shared__ __bf16 Bs[BN * 32];
  int z = blockIdx.z;
  int bm = blockIdx.y * 64, bn = blockIdx.x * BN;
  int tid = threadIdx.x, lane = tid & 63, wv = tid >> 6;
  int wr = wv >> 1, wc = wv & 1;
  int half = lane >> 4, mrow = lane & 15;
  const __bf16* Ab = A + (size_t)z * aZ + (size_t)bm * lda;
  const __bf16* Bb = Bt + (size_t)z * bZ + (size_t)bn * K;
  fx4 acc[2][NI] = {};
  int aslot[2], bslot[NI];
#pragma unroll
  for (int i = 0; i < 2; i++) {
    int row = wr * 32 + i * 16 + mrow;
    aslot[i] = row * 4 + (half ^ ((row >> 1) & 3));
  }
#pragma unroll
  for (int j = 0; j < NI; j++) {
    int row = wc * (NI * 16) + j * 16 + mrow;
    bslot[j] = row * 4 + (half ^ ((row >> 1) & 3));
  }
  for (int k0 = 0; k0 < K; k0 += 32) {
    {
      int c = tid;
      int row = c >> 2;
      int kc = (((c & 3) ^ ((row >> 1) & 3)) << 3);
      __builtin_amdgcn_global_load_lds(
          (const __attribute__((address_space(1))) void*)(Ab +
                                                          (size_t)row * lda +
                                                          k0 + kc),
          (__attribute__((address_space(3))) void*)(As + c * 8), 16, 0, 0);
    }
#pragma unroll
    for (int it = 0; it < NI / 2; it++) {
      int c = tid + it * 256;
      int row = c >> 2;
      int kc = (((c & 3) ^ ((row >> 1) & 3)) << 3);
      __builtin_amdgcn_global_load_lds(
          (const __attribute__((address_space(1))) void*)(Bb + (size_t)row * K +
                                                          k0 + kc),
          (__attribute__((address_space(3))) void*)(Bs + c * 8), 16, 0, 0);
    }
    __syncthreads();
    bf16x8 af[2], bfr[NI];
#pragma unroll
    for (int i = 0; i < 2; i++) af[i] = *(const bf16x8*)(As + aslot[i] * 8);
#pragma unroll
    for (int j = 0; j < NI; j++) bfr[j] = *(const bf16x8*)(Bs + bslot[j] * 8);
#pragma unroll
    for (int i = 0; i < 2; i++)
#pragma unroll
      for (int j = 0; j < NI; j++)
        acc[i][j] = __builtin_amdgcn_mfma_f32_16x16x32_bf16(af[i], bfr[j],
                                                            acc[i][j], 0, 0, 0);
    __syncthreads();
  }
  int doRope = rope && (z < 2);
#pragma unroll
  for (int i = 0; i < 2; i++) {
#pragma unroll
    for (int r = 0; r < 4; r++) {
      int row = bm + wr * 32 + i * 16 + half * 4 + r;
      float rs = rowScale ? rowScale[(size_t)row * rsLd + z] : 1.f;
      float vv[NI];
#pragma unroll
      for (int j = 0; j < NI; j++) {
        int col = bn + wc * (NI * 16) + j * 16 + mrow;
        float val = acc[i][j][r];
        if (bias) val += bias[(size_t)z * biasZ + col];
        if (relu) val = fmaxf(val, 0.f);
        vv[j] = val * rs;
      }
      if (doRope && NI == 4) {
        int spos = row & (S - 1);
#pragma unroll
        for (int jj = 0; jj < 2; jj++) {
          int hd = jj * 16 + mrow;  // 0..31
          float invf = exp2f(hd * -0.4152410118609825f);
          float ang = (float)spos * invf;
          float sn, cs;
          __sincosf(ang, &sn, &cs);
          float a0 = vv[jj], a1 = vv[jj + 2];
          vv[jj] = a0 * cs - a1 * sn;
          vv[jj + 2] = a1 * cs + a0 * sn;
        }
      }
#pragma unroll
      for (int j = 0; j < NI; j++) {
        int col = bn + wc * (NI * 16) + j * 16 + mrow;
        size_t addr = (size_t)z * cZ + (size_t)row * ldc + col;
        if (Cbf)
          Cbf[addr] = (__bf16)vv[j];
        else if (accum)
          C[addr] += vv[j];
        else
          C[addr] = vv[j];
      }
    }
  }
}

// ---------------- fp32 -> bf16 transpose+convert (z-split strides) --------
// src += z*srcZ; dst += (z/zmod)*dstZb + (z%zmod)*dstZa; dst[c*dstLd + r].
__global__ void transpose_cvt(const float* __restrict__ src, long long srcZ,
                              __bf16* __restrict__ dst, int zmod,
                              long long dstZa, long long dstZb, int R, int C,
                              int dstLd) {
  __shared__ float t[32][33];
  int r0 = blockIdx.y * 32, c0 = blockIdx.x * 32;
  int z = blockIdx.z;
  src += (size_t)z * srcZ;
  dst += (size_t)(z / zmod) * dstZb + (size_t)(z % zmod) * dstZa;
  int tx = threadIdx.x, ty = threadIdx.y;
#pragma unroll
  for (int i = 0; i < 4; i++) {
    int r = r0 + ty + i * 8;
    t[ty + i * 8][tx] = src[(size_t)r * C + c0 + tx];
  }
  __syncthreads();
#pragma unroll
  for (int i = 0; i < 4; i++) {
    int c = c0 + ty + i * 8;
    dst[(size_t)c * dstLd + r0 + tx] = (__bf16)t[tx][ty + i * 8];
  }
}

__global__ void cvt_kernel(const float* __restrict__ s, __bf16* __restrict__ d,
                           int n) {
  for (int i = blockIdx.x * 256 + threadIdx.x; i < n; i += gridDim.x * 256)
    d[i] = (__bf16)s[i];
}

// ---------------- concat biases for all layers ---------------------------
__global__ void bias_all(const float* __restrict__ a,
                         const float* __restrict__ b,
                         const float* __restrict__ c, float* __restrict__ dst) {
  int i = blockIdx.x * 256 + threadIdx.x;
  if (i >= LNUM * 3 * D) return;
  int l = i / (3 * D), r = i % (3 * D);
  int w = r / D, d = r % D;
  const float* src = w == 0 ? a : (w == 1 ? b : c);
  dst[i] = src[l * D + d];
}

// ---------------- bf16 MFMA flash attention (RoPE pre-applied) -----------
#define VT_LD 68
#define P_LD 72
__global__ __launch_bounds__(256) void attn_mfma(const __bf16* __restrict__ qb,
                                                 const __bf16* __restrict__ kb,
                                                 const __bf16* __restrict__ vb,
                                                 __bf16* __restrict__ obf) {
  __shared__ __bf16 Kt[64 * 64];     // swizzled chunks, 8 KB
  __shared__ __bf16 Vt[HD * VT_LD];  // [d][t] transposed, 8.5 KB
  __shared__ __bf16 Pb[64 * P_LD];   // per-wave-private P slices, 9 KB
  int q0 = blockIdx.x * 64, hh = blockIdx.y, b = blockIdx.z;
  int tid = threadIdx.x, lane = tid & 63, wv = tid >> 6;
  int col = lane & 15, half = lane >> 4;
  const size_t headoff = (size_t)hh * HD;
  const float scale = 0.125f;

  const __bf16* qbase =
      qb + ((size_t)(b * S + q0 + wv * 16 + col)) * D + headoff;
  bf16x8 qf0 = *(const bf16x8*)(qbase + half * 8);
  bf16x8 qf1 = *(const bf16x8*)(qbase + 32 + half * 8);

  fx4 Oacc[4] = {};
  float m_i[4] = {-1e30f, -1e30f, -1e30f, -1e30f};
  float l_i[4] = {0.f, 0.f, 0.f, 0.f};

  for (int t0 = 0; t0 < S; t0 += 64) {
    __syncthreads();
    // K tile: direct global->LDS, XOR chunk swizzle. LDS[row][sl] holds
    // global chunk sl^(row&7) of K row t0+row.
#pragma unroll
    for (int it = 0; it < 2; it++) {
      int c = tid + it * 256;
      int row = c >> 3, sl = c & 7;
      int g = sl ^ (row & 7);
      __builtin_amdgcn_global_load_lds(
          (const __attribute__((address_space(1))) void*)(kb +
                                                          ((size_t)(b * S + t0 +
                                                                    row)) *
                                                              D +
                                                          headoff + g * 8),
          (__attribute__((address_space(3))) void*)(Kt + c * 8), 16, 0, 0);
    }
    // V tile transposed: packed b32 writes (pairs along t)
    {
      int dgroup = tid & 7, tpair = tid >> 3;
      int t = tpair * 2;
      bf16x8 v0 = *(const bf16x8*)(vb + ((size_t)(b * S + t0 + t)) * D +
                                   headoff + dgroup * 8);
      bf16x8 v1 = *(const bf16x8*)(vb + ((size_t)(b * S + t0 + t + 1)) * D +
                                   headoff + dgroup * 8);
#pragma unroll
      for (int j = 0; j < 8; j++) {
        union {
          __bf16 h[2];
          unsigned int u;
        } pk;
        pk.h[0] = v0[j];
        pk.h[1] = v1[j];
        *(unsigned int*)(Vt + (dgroup * 8 + j) * VT_LD + t) = pk.u;
      }
    }
    __syncthreads();

    // S = Q @ K^T (B-frag rows from swizzled Kt, conflict-free b128)
    fx4 sacc[4] = {};
#pragma unroll
    for (int n = 0; n < 4; n++) {
      int rowk = n * 16 + col;
      const __bf16* kp = Kt + rowk * 64;
      bf16x8 b0 = *(const bf16x8*)(kp + ((half ^ (rowk & 7)) << 3));
      bf16x8 b1 = *(const bf16x8*)(kp + (((4 + half) ^ (rowk & 7)) << 3));
      sacc[n] =
          __builtin_amdgcn_mfma_f32_16x16x32_bf16(qf0, b0, sacc[n], 0, 0, 0);
      sacc[n] =
          __builtin_amdgcn_mfma_f32_16x16x32_bf16(qf1, b1, sacc[n], 0, 0, 0);
    }
    // online softmax
#pragma unroll
    for (int r = 0; r < 4; r++) {
      float mx =
          fmaxf(fmaxf(sacc[0][r], sacc[1][r]), fmaxf(sacc[2][r], sacc[3][r]));
#pragma unroll
      for (int msk = 1; msk < 16; msk <<= 1)
        mx = fmaxf(mx, __shfl_xor(mx, msk));
      float nm = fmaxf(m_i[r], mx * scale);
      float alpha = __expf(m_i[r] - nm);
      m_i[r] = nm;
      l_i[r] *= alpha;
#pragma unroll
      for (int n = 0; n < 4; n++) Oacc[n][r] *= alpha;
      float part = 0.f;
      int prow = (wv * 16 + half * 4 + r) * P_LD;
#pragma unroll
      for (int n = 0; n < 4; n++) {
        float p = __expf(sacc[n][r] * scale - nm);
        part += p;
        Pb[prow + n * 16 + col] = (__bf16)p;
      }
#pragma unroll
      for (int msk = 1; msk < 16; msk <<= 1) part += __shfl_xor(part, msk);
      l_i[r] += part;
    }
    // O += P @ V
#pragma unroll
    for (int k0 = 0; k0 < 2; k0++) {
      bf16x8 af =
          *(const bf16x8*)(Pb + (wv * 16 + col) * P_LD + k0 * 32 + half * 8);
#pragma unroll
      for (int n = 0; n < 4; n++) {
        const __bf16* vp = Vt + (n * 16 + col) * VT_LD + k0 * 32 + half * 8;
        union {
          bf16x4 h[2];
          bf16x8 v;
        } u;
        u.h[0] = *(const bf16x4*)vp;
        u.h[1] = *(const bf16x4*)(vp + 4);
        Oacc[n] =
            __builtin_amdgcn_mfma_f32_16x16x32_bf16(af, u.v, Oacc[n], 0, 0, 0);
      }
    }
  }
#pragma unroll
  for (int r = 0; r < 4; r++) {
    float inv = 1.f / l_i[r];
    int row = q0 + wv * 16 + half * 4 + r;
    __bf16* op = obf + ((size_t)(b * S + row)) * D + headoff;
#pragma unroll
    for (int n = 0; n < 4; n++) op[n * 16 + col] = (__bf16)(Oacc[n][r] * inv);
  }
}

// ---------------- final head: last token only ----------------
__global__ __launch_bounds__(256) void final_kernel(
    const float* __restrict__ h, const float* __restrict__ tg,
    const float* __restrict__ tb, const float* __restrict__ dg,
    const float* __restrict__ db, const float* __restrict__ ow,
    const float* __restrict__ ob, float* __restrict__ out) {
  int b = blockIdx.x;
  int tid = threadIdx.x;
  __shared__ float scratch[4];
  __shared__ float yf[D];
  const float* p = h + ((size_t)(b * S + (S - 1))) * D;
  float x[4];
  float s = 0.f, sq = 0.f;
#pragma unroll
  for (int i = 0; i < 4; i++) {
    x[i] = p[tid + i * 256];
    s += x[i];
    sq += x[i] * x[i];
  }
  s = block_reduce_sum256(s, scratch);
  sq = block_reduce_sum256(sq, scratch);
  float mean = s * (1.f / D);
  float inv = rsqrtf(sq * (1.f / D) - mean * mean + EPS);
  float y[4];
  s = 0.f;
  sq = 0.f;
#pragma unroll
  for (int i = 0; i < 4; i++) {
    int d = tid + i * 256;
    y[i] = (x[i] - mean) * inv * tg[d] + tb[d];
    s += y[i];
    sq += y[i] * y[i];
  }
  s = block_reduce_sum256(s, scratch);
  sq = block_reduce_sum256(sq, scratch);
  float mean2 = s * (1.f / D);
  float inv2 = rsqrtf(sq * (1.f / D) - mean2 * mean2 + EPS);
#pragma unroll
  for (int i = 0; i < 4; i++) {
    int d = tid + i * 256;
    yf[d] = (y[i] - mean2) * inv2 * dg[d] + db[d];
  }
  __syncthreads();
  for (int oo = 0; oo < NOUT; oo++) {
    float part = 0.f;
    for (int d = tid; d < D; d += 256) part += yf[d] * ow[(size_t)oo * D + d];
    part = block_reduce_sum256(part, scratch);
    if (tid == 0) out[b * NOUT + oo] = part + ob[oo];
  }
}

extern "C" void kernel_launch(void* const* d_in, const int* in_sizes, int n_in,
                              void* d_out, int out_size, void* d_ws,
                              size_t ws_size, hipStream_t stream) {
  const float* x = (const float*)d_in[0];
  const float* ln1_g = (const float*)d_in[1];
  const float* ln1_b = (const float*)d_in[2];
  const float* qw = (const float*)d_in[3];
  const float* qb_ = (const float*)d_in[4];
  const float* kw = (const float*)d_in[5];
  const float* kb_ = (const float*)d_in[6];
  const float* vw = (const float*)d_in[7];
  const float* vb_ = (const float*)d_in[8];
  const float* ow = (const float*)d_in[9];
  const float* ob = (const float*)d_in[10];
  const float* ln2_g = (const float*)d_in[11];
  const float* ln2_b = (const float*)d_in[12];
  const float* selw = (const float*)d_in[13];
  const float* w1 = (const float*)d_in[14];
  const float* w2 = (const float*)d_in[15];
  const float* lntg = (const float*)d_in[16];
  const float* lntb = (const float*)d_in[17];
  const float* lndg = (const float*)d_in[18];
  const float* lndb = (const float*)d_in[19];
  const float* inw = (const float*)d_in[20];
  const float* inb = (const float*)d_in[21];
  const float* outw = (const float*)d_in[22];
  const float* outb = (const float*)d_in[23];
  float* out = (float*)d_out;

  // ---- workspace layout (~64 MB) ----
  float* h = (float*)d_ws;                            // TOK*D f32
  float* gm = h + (size_t)TOK * D;                    // TOK*E
  float* qkvbias = gm + (size_t)TOK * E;              // L*3*D
  __bf16* xnb = (__bf16*)(qkvbias + LNUM * 3 * D);    // TOK*D
  __bf16* qkvbf = xnb + (size_t)TOK * D;              // 3*TOK*D
  __bf16* obf = qkvbf + (size_t)3 * TOK * D;          // TOK*D
  __bf16* qkvt = obf + (size_t)TOK * D;               // L*3*D*D
  __bf16* owt = qkvt + (size_t)LNUM * 3 * D * D;      // L*D*D
  __bf16* w1t = owt + (size_t)LNUM * D * D;           // L*E*EH*D
  __bf16* w2t = w1t + (size_t)LNUM * E * EH * D;      // L*D*E*EH
  __bf16* midb = qkvbf;  // alias: qkv dead before MoE, revived next layer

  __bf16* qbf = qkvbf;
  __bf16* kbf = qkvbf + (size_t)TOK * D;
  __bf16* vbf = qkvbf + (size_t)2 * TOK * D;

  // ---- weight prep, all layers, 7 launches ----
  transpose_cvt<<<dim3(32, 32, LNUM), dim3(32, 8), 0, stream>>>(
      qw, (long long)D * D, qkvt, 1024, (long long)3 * D * D, 0, D, D, D);
  transpose_cvt<<<dim3(32, 32, LNUM), dim3(32, 8), 0, stream>>>(
      kw, (long long)D * D, qkvt + (size_t)D * D, 1024, (long long)3 * D * D, 0,
      D, D, D);
  transpose_cvt<<<dim3(32, 32, LNUM), dim3(32, 8), 0, stream>>>(
      vw, (long long)D * D, qkvt + (size_t)2 * D * D, 1024,
      (long long)3 * D * D, 0, D, D, D);
  cvt_kernel<<<1024, 256, 0, stream>>>(ow, owt, LNUM * D * D);
  transpose_cvt<<<dim3(EH / 32, D / 32, LNUM * E), dim3(32, 8), 0, stream>>>(
      w1, (long long)D * EH, w1t, 1024, (long long)EH * D, 0, D, EH, D);
  transpose_cvt<<<dim3(D / 32, EH / 32, LNUM * E), dim3(32, 8), 0, stream>>>(
      w2, (long long)EH * D, w2t, E, EH, (long long)D * E * EH, EH, D, E * EH);
  bias_all<<<(LNUM * 3 * D + 255) / 256, 256, 0, stream>>>(qb_, kb_, vb_,
                                                           qkvbias);

  gemm_kernel<<<dim3(D / 64, TOK / 64), 256, 0, stream>>>(x, inw, inb, h, TOK,
                                                          D, DIN);
  for (int l = 0; l < LNUM; l++) {
    ln_bf_kernel<<<TOK, 256, 0, stream>>>(h, ln1_g + l * D, ln1_b + l * D, xnb);
    // q,k,v = rope(xn @ W + b) -> bf16 (z=0..2), 64x128 tile
    mfma_gemm<4><<<dim3(D / 128, TOK / 64, 3), 256, 0, stream>>>(
        xnb, D, 0, qkvt + (size_t)l * 3 * D * D, (long long)D * D,
        qkvbias + l * 3 * D, D, nullptr, qkvbf, D, (long long)TOK * D, nullptr,
        0, D, 0, 0, 1);
    attn_mfma<<<dim3(S / 64, H, B), 256, 0, stream>>>(qbf, kbf, vbf, obf);
    // h += o @ ow^T + ob
    mfma_gemm<2><<<dim3(D / 64, TOK / 64, 1), 256, 0, stream>>>(
        obf, D, 0, owt + (size_t)l * D * D, 0, ob + l * D, 0, h, nullptr, D, 0,
        nullptr, 0, D, 1, 0, 0);
    ln_gate_kernel<<<TOK, 256, 0, stream>>>(h, ln2_g + l * D, ln2_b + l * D,
                                            selw + (size_t)l * D * E, xnb, gm);
    // mid = relu(xn @ w1[e]) * gate  (z=8)
    mfma_gemm<2><<<dim3(EH / 64, TOK / 64, E), 256, 0, stream>>>(
        xnb, D, 0, w1t + (size_t)l * E * EH * D, (long long)EH * D, nullptr, 0,
        nullptr, midb, E * EH, EH, gm, E, D, 0, 1, 0);
    // h += mid @ w2stacked (K = 2048)
    mfma_gemm<2><<<dim3(D / 64, TOK / 64, 1), 256, 0, stream>>>(
        midb, E * EH, 0, w2t + (size_t)l * D * E * EH, 0, nullptr, 0, h,
        nullptr, D, 0, nullptr, 0, E * EH, 1, 0, 0);
  }
  final_kernel<<<B, 256, 0, stream>>>(h, lntg, lntb, lndg, lndb, outw, outb,
                                      out);
}